// Round 2
// baseline (13997.305 us; speedup 1.0000x reference)
//
#include <hip/hip_runtime.h>
#include <math.h>

#define BATCH 32
#define LHIST 96
#define NVARS 862
#define LFUT  96
#define DMODEL 512
#define DINNER 512
#define DSTATE 32
#define DTRANK 32

// ---------------------------------------------------------------- mean/std
// per token (b,n) within chunk: mean/std over L of history[b,l,n,0]; write
// normalized series token-major into xin[local_tok*96 + l].
__global__ void meanstd_k(const float* __restrict__ hist, float* __restrict__ xin,
                          float* __restrict__ meanb, float* __restrict__ stdb,
                          int b0, int CB) {
    int idx = blockIdx.x * blockDim.x + threadIdx.x;
    if (idx >= CB * NVARS) return;
    int b = b0 + idx / NVARS, n = idx % NVARS;
    const float* p = hist + (size_t)b * LHIST * NVARS + n;
    float s = 0.f;
    for (int l = 0; l < LHIST; l++) s += p[(size_t)l * NVARS];
    float mean = s * (1.f / LHIST);
    float v = 0.f;
    for (int l = 0; l < LHIST; l++) { float d = p[(size_t)l * NVARS] - mean; v += d * d; }
    v *= (1.f / LHIST);
    float sd = sqrtf(v + 1e-5f);
    float inv = 1.f / sd;
    meanb[idx] = mean;
    stdb[idx]  = sd;
    float* o = xin + (size_t)idx * LHIST;
    for (int l = 0; l < LHIST; l++) o[l] = (p[(size_t)l * NVARS] - mean) * inv;
}

// ---------------------------------------------------------------- GEMM
// C[M,N] = act(A[M,K] @ W[K,N] + bias) (+ C if accum). 128x128 tile, BK=8,
// 256 threads, 8x8 per thread. K must be a multiple of 8 (96, 512, 32 all ok).
#define GBM 128
#define GBN 128
#define GBK 8

__global__ __launch_bounds__(256)
void gemm_k(const float* __restrict__ A, int lda,
            const float* __restrict__ W, int ldw,
            const float* __restrict__ bias,
            float* __restrict__ C, int ldc,
            int M, int N, int K, int act, int accum) {
    __shared__ float As[GBK][GBM];
    __shared__ float Ws[GBK][GBN];
    int tid = threadIdx.x;
    int gm0 = blockIdx.y * GBM, gn0 = blockIdx.x * GBN;
    int ty = tid >> 4, tx = tid & 15;

    float acc[8][8];
#pragma unroll
    for (int i = 0; i < 8; i++)
#pragma unroll
        for (int j = 0; j < 8; j++) acc[i][j] = 0.f;

    int lm = tid >> 1;            // 0..127 (A row within tile)
    int lk = (tid & 1) * 4;       // 0 or 4 (A k-offset)
    int wk = tid >> 5;            // 0..7   (W k within tile)
    int wn = (tid & 31) * 4;      // 0..124 (W col within tile)

    for (int k0 = 0; k0 < K; k0 += GBK) {
        float4 av = make_float4(0.f, 0.f, 0.f, 0.f);
        if (gm0 + lm < M)
            av = *(const float4*)(A + (size_t)(gm0 + lm) * lda + k0 + lk);
        float4 wv;
        int wc = gn0 + wn;
        const float* wp = W + (size_t)(k0 + wk) * ldw;
        if (wc + 3 < N) {
            wv = *(const float4*)(wp + wc);
        } else {
            wv.x = (wc + 0 < N) ? wp[wc + 0] : 0.f;
            wv.y = (wc + 1 < N) ? wp[wc + 1] : 0.f;
            wv.z = (wc + 2 < N) ? wp[wc + 2] : 0.f;
            wv.w = (wc + 3 < N) ? wp[wc + 3] : 0.f;
        }
        __syncthreads();
        As[lk + 0][lm] = av.x;
        As[lk + 1][lm] = av.y;
        As[lk + 2][lm] = av.z;
        As[lk + 3][lm] = av.w;
        *(float4*)&Ws[wk][wn] = wv;
        __syncthreads();
#pragma unroll
        for (int k = 0; k < GBK; k++) {
            float4 a0 = *(const float4*)&As[k][ty * 8];
            float4 a1 = *(const float4*)&As[k][ty * 8 + 4];
            float4 w0 = *(const float4*)&Ws[k][tx * 8];
            float4 w1 = *(const float4*)&Ws[k][tx * 8 + 4];
            float aa[8] = {a0.x, a0.y, a0.z, a0.w, a1.x, a1.y, a1.z, a1.w};
            float ww[8] = {w0.x, w0.y, w0.z, w0.w, w1.x, w1.y, w1.z, w1.w};
#pragma unroll
            for (int i = 0; i < 8; i++)
#pragma unroll
                for (int j = 0; j < 8; j++) acc[i][j] += aa[i] * ww[j];
        }
    }

#pragma unroll
    for (int i = 0; i < 8; i++) {
        int r = gm0 + ty * 8 + i;
        if (r >= M) continue;
        float* crow = C + (size_t)r * ldc;
#pragma unroll
        for (int j = 0; j < 8; j++) {
            int c = gn0 + tx * 8 + j;
            if (c >= N) continue;
            float v = acc[i][j];
            if (bias) v += bias[c];
            if (act == 1) v = fmaxf(v, 0.f);                         // relu
            else if (act == 2) v = (v > 20.f) ? v : log1pf(expf(v)); // softplus
            if (accum) v += crow[c];
            crow[c] = v;
        }
    }
}

// ---------------------------------------------------------------- conv+silu
// causal depthwise conv (width 2) + silu. rev=0: uses u[t-1]; rev=1: uses
// u[t+1] (== mamba on reversed sequence, outputs kept in original order).
__global__ void convsilu_k(const float* __restrict__ u, const float* __restrict__ cw,
                           const float* __restrict__ cb, float* __restrict__ uc,
                           int rev, int R) {
    size_t idx = (size_t)blockIdx.x * blockDim.x + threadIdx.x;
    if (idx >= (size_t)R * DINNER) return;
    int e = (int)(idx & (DINNER - 1));
    int m = (int)(idx >> 9);
    int t = m % NVARS;
    float cur = u[idx];
    float other = 0.f;
    if (!rev) { if (t > 0)          other = u[idx - DINNER]; }
    else      { if (t < NVARS - 1)  other = u[idx + DINNER]; }
    float v = cw[e * 2] * other + cw[e * 2 + 1] * cur + cb[e];
    float sig = 1.f / (1.f + __expf(-v));
    uc[idx] = v * sig;
}

// ---------------------------------------------------------------- scan
// thread per (local b, e): 32-state recurrence over T=NVARS, direction per
// `rev`. Fuses + u*D and * silu(z) gating. y may alias z (same-element
// read-before-write within one thread).
__global__ __launch_bounds__(64)
void scan_k(const float* __restrict__ delta, const float* __restrict__ uc,
            const float* __restrict__ z, const float* __restrict__ xdbc,
            const float* __restrict__ A_log, const float* __restrict__ Dp,
            float* __restrict__ y, int rev, int CB) {
    int idx = blockIdx.x * blockDim.x + threadIdx.x;
    if (idx >= CB * DINNER) return;
    int b = idx >> 9, e = idx & (DINNER - 1);

    float A[DSTATE], h[DSTATE];
#pragma unroll
    for (int s = 0; s < DSTATE; s++) {
        A[s] = -__expf(A_log[e * DSTATE + s]);
        h[s] = 0.f;
    }
    float Dv = Dp[e];
    for (int i = 0; i < NVARS; i++) {
        int t = rev ? (NVARS - 1 - i) : i;
        size_t m = (size_t)b * NVARS + t;
        size_t me = m * DINNER + e;
        float d  = delta[me];
        float uv = uc[me];
        float zz = z[me];
        float du = d * uv;
        const float* Bp = xdbc + m * 96 + DTRANK;
        const float* Cp = Bp + DSTATE;
        float accv = 0.f;
#pragma unroll
        for (int s = 0; s < DSTATE; s++) {
            h[s] = __expf(d * A[s]) * h[s] + du * Bp[s];
            accv += h[s] * Cp[s];
        }
        float sig = 1.f / (1.f + __expf(-zz));
        y[me] = (accv + uv * Dv) * (zz * sig);
    }
}

// ---------------------------------------------------------------- layernorm
// one wave per row of 512; out = LN(in1 (+ in2)) * w + b. Safe in-place.
__global__ __launch_bounds__(64)
void ln_k(const float* __restrict__ in1, const float* __restrict__ in2,
          const float* __restrict__ w, const float* __restrict__ b,
          float* __restrict__ out) {
    int row = blockIdx.x;
    int lane = threadIdx.x;
    const float* p1 = in1 + (size_t)row * DMODEL;
    const float* p2 = in2 ? in2 + (size_t)row * DMODEL : nullptr;
    float v[8];
#pragma unroll
    for (int i = 0; i < 8; i++) {
        int c = lane + i * 64;
        v[i] = p1[c];
        if (p2) v[i] += p2[c];
    }
    float s = 0.f;
#pragma unroll
    for (int i = 0; i < 8; i++) s += v[i];
#pragma unroll
    for (int off = 32; off >= 1; off >>= 1) s += __shfl_xor(s, off);
    float mean = s * (1.f / DMODEL);
    float q = 0.f;
#pragma unroll
    for (int i = 0; i < 8; i++) { float d = v[i] - mean; q += d * d; }
#pragma unroll
    for (int off = 32; off >= 1; off >>= 1) q += __shfl_xor(q, off);
    float rs = rsqrtf(q * (1.f / DMODEL) + 1e-5f);
    float* o = out + (size_t)row * DMODEL;
#pragma unroll
    for (int i = 0; i < 8; i++) {
        int c = lane + i * 64;
        o[c] = (v[i] - mean) * rs * w[c] + b[c];
    }
}

// ---------------------------------------------------------------- de-norm + transpose
// out[b0+bl, l, n] = dec[(bl*N+n)*96 + l] * std[tok] + mean[tok]
__global__ void final_k(const float* __restrict__ dec, const float* __restrict__ meanb,
                        const float* __restrict__ stdb, float* __restrict__ out,
                        int b0, int CB) {
    int idx = blockIdx.x * blockDim.x + threadIdx.x;
    if (idx >= CB * LFUT * NVARS) return;
    int n = idx % NVARS;
    int r = idx / NVARS;
    int l = r % LFUT;
    int bl = r / LFUT;
    int tok = bl * NVARS + n;
    out[(size_t)((b0 + bl) * LFUT + l) * NVARS + n] =
        dec[(size_t)tok * LFUT + l] * stdb[tok] + meanb[tok];
}

// ---------------------------------------------------------------- launch
extern "C" void kernel_launch(void* const* d_in, const int* in_sizes, int n_in,
                              void* d_out, int out_size, void* d_ws, size_t ws_size,
                              hipStream_t stream) {
    const float* hist    = (const float*)d_in[0];
    const float* emb_w   = (const float*)d_in[1];
    const float* emb_b   = (const float*)d_in[2];
    const float* m_in_w  = (const float*)d_in[3];   // [2][2][512][1024]
    const float* m_conv_w= (const float*)d_in[4];   // [2][2][512][2]
    const float* m_conv_b= (const float*)d_in[5];   // [2][2][512]
    const float* m_x_w   = (const float*)d_in[6];   // [2][2][512][96]
    const float* m_dt_w  = (const float*)d_in[7];   // [2][2][32][512]
    const float* m_dt_b  = (const float*)d_in[8];   // [2][2][512]
    const float* m_A_log = (const float*)d_in[9];   // [2][2][512][32]
    const float* m_D     = (const float*)d_in[10];  // [2][2][512]
    const float* m_out_w = (const float*)d_in[11];  // [2][2][512][512]
    const float* ffn_w1  = (const float*)d_in[12];  // [2][512][512]
    const float* ffn_b1  = (const float*)d_in[13];
    const float* ffn_w2  = (const float*)d_in[14];
    const float* ffn_b2  = (const float*)d_in[15];
    const float* norm1_w = (const float*)d_in[16];
    const float* norm1_b = (const float*)d_in[17];
    const float* norm2_w = (const float*)d_in[18];
    const float* norm2_b = (const float*)d_in[19];
    const float* normf_w = (const float*)d_in[20];
    const float* normf_b = (const float*)d_in[21];
    const float* proj_w  = (const float*)d_in[22];  // [512][96]
    const float* proj_b  = (const float*)d_in[23];

    float* out = (float*)d_out;
    float* ws  = (float*)d_ws;

    // ---- adaptive batch chunking so the workspace footprint fits ws_size.
    // per-chunk floats: R*(5*512 + 2*96 + 2), R = CB*NVARS
    int CB = BATCH;
    while (CB > 1 && (size_t)CB * NVARS * 2754u * 4u > ws_size) CB >>= 1;
    const int R = CB * NVARS;               // rows (tokens) per chunk
    const size_t SB = (size_t)R * DMODEL;

    float* x     = ws;                 // activations
    float* acc   = ws + 1 * SB;        // fwd+rev out-proj accumulator
    float* ubuf  = ws + 2 * SB;        // u -> delta -> ffn mid (reused)
    float* zbuf  = ws + 3 * SB;        // z -> y (scan output, aliased)
    float* ucbuf = ws + 4 * SB;        // conv(u) -> ffn out (reused)
    float* xdbc  = ws + 5 * SB;        // [R,96] dt/B/C, later dec
    float* xin   = xdbc + (size_t)R * 96;   // [R,96] normalized history
    float* meanb = xin  + (size_t)R * 96;
    float* stdb  = meanb + R;

    auto gemm = [&](const float* A, int lda, const float* W, int ldw,
                    const float* bias, float* C, int ldc,
                    int M, int N, int K, int act, int accum) {
        dim3 grid((N + GBN - 1) / GBN, (M + GBM - 1) / GBM);
        gemm_k<<<grid, 256, 0, stream>>>(A, lda, W, ldw, bias, C, ldc, M, N, K, act, accum);
    };

    for (int b0 = 0; b0 < BATCH; b0 += CB) {
        // input normalization + inverted embedding
        meanstd_k<<<(R + 255) / 256, 256, 0, stream>>>(hist, xin, meanb, stdb, b0, CB);
        gemm(xin, LHIST, emb_w, DMODEL, emb_b, x, DMODEL, R, DMODEL, LHIST, 0, 0);

        for (int l = 0; l < 2; l++) {
            for (int dir = 0; dir < 2; dir++) {
                size_t p = (size_t)(l * 2 + dir);
                const float* inw  = m_in_w  + p * DMODEL * (2 * DINNER);
                const float* cw   = m_conv_w + p * DINNER * 2;
                const float* cb   = m_conv_b + p * DINNER;
                const float* xw   = m_x_w   + p * DINNER * 96;
                const float* dtw  = m_dt_w  + p * DTRANK * DINNER;
                const float* dtb  = m_dt_b  + p * DINNER;
                const float* alog = m_A_log + p * DINNER * DSTATE;
                const float* Dp   = m_D     + p * DINNER;
                const float* ow   = m_out_w + p * DINNER * DMODEL;

                // u, z = split(x @ in_w)
                gemm(x, DMODEL, inw,       2 * DINNER, nullptr, ubuf, DINNER, R, DINNER, DMODEL, 0, 0);
                gemm(x, DMODEL, inw + 512, 2 * DINNER, nullptr, zbuf, DINNER, R, DINNER, DMODEL, 0, 0);
                // causal depthwise conv + silu
                convsilu_k<<<(unsigned)(((size_t)R * DINNER + 255) / 256), 256, 0, stream>>>(
                    ubuf, cw, cb, ucbuf, dir, R);
                // dt/B/C projection
                gemm(ucbuf, DINNER, xw, 96, nullptr, xdbc, 96, R, 96, DINNER, 0, 0);
                // delta = softplus(dt @ dt_w + dt_b)   (into ubuf, u is dead)
                gemm(xdbc, 96, dtw, DINNER, dtb, ubuf, DINNER, R, DINNER, DTRANK, 2, 0);
                // selective scan + gating (y aliases z)
                scan_k<<<(CB * DINNER + 63) / 64, 64, 0, stream>>>(
                    ubuf, ucbuf, zbuf, xdbc, alog, Dp, zbuf, dir, CB);
                // acc (=)+= y @ out_w   (dir 0 overwrites, dir 1 accumulates)
                gemm(zbuf, DINNER, ow, DMODEL, nullptr, acc, DMODEL, R, DMODEL, DINNER, 0, dir);
            }
            // x = LN(x + fwd + rev)
            ln_k<<<R, 64, 0, stream>>>(acc, x, norm1_w + l * DMODEL, norm1_b + l * DMODEL, x);
            // FFN
            gemm(x, DMODEL, ffn_w1 + (size_t)l * DMODEL * DMODEL, DMODEL,
                 ffn_b1 + l * DMODEL, ubuf, DMODEL, R, DMODEL, DMODEL, 1, 0);
            gemm(ubuf, DMODEL, ffn_w2 + (size_t)l * DMODEL * DMODEL, DMODEL,
                 ffn_b2 + l * DMODEL, ucbuf, DMODEL, R, DMODEL, DMODEL, 0, 0);
            // x = LN(x + ffn)
            ln_k<<<R, 64, 0, stream>>>(x, ucbuf, norm2_w + l * DMODEL, norm2_b + l * DMODEL, x);
        }

        // final LN + projection + de-normalization
        ln_k<<<R, 64, 0, stream>>>(x, nullptr, normf_w, normf_b, x);
        gemm(x, DMODEL, proj_w, LFUT, proj_b, xdbc, LFUT, R, LFUT, DMODEL, 0, 0);
        final_k<<<(CB * LFUT * NVARS + 255) / 256, 256, 0, stream>>>(
            xdbc, meanb, stdb, out, b0, CB);
    }
}

// Round 3
// 7013.978 us; speedup vs baseline: 1.9956x; 1.9956x over previous
//
#include <hip/hip_runtime.h>
#include <math.h>

#define BATCH 32
#define LHIST 96
#define NVARS 862
#define LFUT  96
#define DMODEL 512
#define DINNER 512
#define DSTATE 32
#define DTRANK 32
#define SCAN_C 16                      // scan chunks per sequence
#define SCAN_TC ((NVARS + SCAN_C - 1) / SCAN_C)   // 54 timesteps per chunk

// ---------------------------------------------------------------- mean/std
__global__ void meanstd_k(const float* __restrict__ hist, float* __restrict__ xin,
                          float* __restrict__ meanb, float* __restrict__ stdb,
                          int b0, int CB) {
    int idx = blockIdx.x * blockDim.x + threadIdx.x;
    if (idx >= CB * NVARS) return;
    int b = b0 + idx / NVARS, n = idx % NVARS;
    const float* p = hist + (size_t)b * LHIST * NVARS + n;
    float s = 0.f;
    for (int l = 0; l < LHIST; l++) s += p[(size_t)l * NVARS];
    float mean = s * (1.f / LHIST);
    float v = 0.f;
    for (int l = 0; l < LHIST; l++) { float d = p[(size_t)l * NVARS] - mean; v += d * d; }
    v *= (1.f / LHIST);
    float sd = sqrtf(v + 1e-5f);
    float inv = 1.f / sd;
    meanb[idx] = mean;
    stdb[idx]  = sd;
    float* o = xin + (size_t)idx * LHIST;
    for (int l = 0; l < LHIST; l++) o[l] = (p[(size_t)l * NVARS] - mean) * inv;
}

// ---------------------------------------------------------------- GEMM
// C[M,N] = act(A[M,K] @ W[K,N] + bias) (+ C if accum). 128x128 tile, BK=8.
#define GBM 128
#define GBN 128
#define GBK 8

__global__ __launch_bounds__(256)
void gemm_k(const float* __restrict__ A, int lda,
            const float* __restrict__ W, int ldw,
            const float* __restrict__ bias,
            float* __restrict__ C, int ldc,
            int M, int N, int K, int act, int accum) {
    __shared__ float As[GBK][GBM];
    __shared__ float Ws[GBK][GBN];
    int tid = threadIdx.x;
    int gm0 = blockIdx.y * GBM, gn0 = blockIdx.x * GBN;
    int ty = tid >> 4, tx = tid & 15;

    float acc[8][8];
#pragma unroll
    for (int i = 0; i < 8; i++)
#pragma unroll
        for (int j = 0; j < 8; j++) acc[i][j] = 0.f;

    int lm = tid >> 1;            // 0..127 (A row within tile)
    int lk = (tid & 1) * 4;       // 0 or 4 (A k-offset)
    int wk = tid >> 5;            // 0..7   (W k within tile)
    int wn = (tid & 31) * 4;      // 0..124 (W col within tile)

    for (int k0 = 0; k0 < K; k0 += GBK) {
        float4 av = make_float4(0.f, 0.f, 0.f, 0.f);
        if (gm0 + lm < M)
            av = *(const float4*)(A + (size_t)(gm0 + lm) * lda + k0 + lk);
        float4 wv;
        int wc = gn0 + wn;
        const float* wp = W + (size_t)(k0 + wk) * ldw;
        if (wc + 3 < N) {
            wv = *(const float4*)(wp + wc);
        } else {
            wv.x = (wc + 0 < N) ? wp[wc + 0] : 0.f;
            wv.y = (wc + 1 < N) ? wp[wc + 1] : 0.f;
            wv.z = (wc + 2 < N) ? wp[wc + 2] : 0.f;
            wv.w = (wc + 3 < N) ? wp[wc + 3] : 0.f;
        }
        __syncthreads();
        As[lk + 0][lm] = av.x;
        As[lk + 1][lm] = av.y;
        As[lk + 2][lm] = av.z;
        As[lk + 3][lm] = av.w;
        *(float4*)&Ws[wk][wn] = wv;
        __syncthreads();
#pragma unroll
        for (int k = 0; k < GBK; k++) {
            float4 a0 = *(const float4*)&As[k][ty * 8];
            float4 a1 = *(const float4*)&As[k][ty * 8 + 4];
            float4 w0 = *(const float4*)&Ws[k][tx * 8];
            float4 w1 = *(const float4*)&Ws[k][tx * 8 + 4];
            float aa[8] = {a0.x, a0.y, a0.z, a0.w, a1.x, a1.y, a1.z, a1.w};
            float ww[8] = {w0.x, w0.y, w0.z, w0.w, w1.x, w1.y, w1.z, w1.w};
#pragma unroll
            for (int i = 0; i < 8; i++)
#pragma unroll
                for (int j = 0; j < 8; j++) acc[i][j] += aa[i] * ww[j];
        }
    }

#pragma unroll
    for (int i = 0; i < 8; i++) {
        int r = gm0 + ty * 8 + i;
        if (r >= M) continue;
        float* crow = C + (size_t)r * ldc;
#pragma unroll
        for (int j = 0; j < 8; j++) {
            int c = gn0 + tx * 8 + j;
            if (c >= N) continue;
            float v = acc[i][j];
            if (bias) v += bias[c];
            if (act == 1) v = fmaxf(v, 0.f);                         // relu
            else if (act == 2) v = (v > 20.f) ? v : log1pf(expf(v)); // softplus
            if (accum) v += crow[c];
            crow[c] = v;
        }
    }
}

// ---------------------------------------------------------------- conv+silu
__global__ void convsilu_k(const float* __restrict__ u, const float* __restrict__ cw,
                           const float* __restrict__ cb, float* __restrict__ uc,
                           int rev, int R) {
    size_t idx = (size_t)blockIdx.x * blockDim.x + threadIdx.x;
    if (idx >= (size_t)R * DINNER) return;
    int e = (int)(idx & (DINNER - 1));
    int m = (int)(idx >> 9);
    int t = m % NVARS;
    float cur = u[idx];
    float other = 0.f;
    if (!rev) { if (t > 0)          other = u[idx - DINNER]; }
    else      { if (t < NVARS - 1)  other = u[idx + DINNER]; }
    float v = cw[e * 2] * other + cw[e * 2 + 1] * cur + cb[e];
    float sig = 1.f / (1.f + __expf(-v));
    uc[idx] = v * sig;
}

// ---------------------------------------------------------------- chunked scan
// Diagonal linear recurrence h <- exp(d*A)*h + d*u*B, chunked over time for
// parallelism. Logical time tau = 0..T-1; physical t = rev ? T-1-tau : tau.
// Lane layout: be = b*512+e contiguous -> coalesced loads, B/C wave-broadcast.

// Pass A: per (chunk, be): local scan from h=0; store Hpart[c][s][be], Sd[c][be].
__global__ __launch_bounds__(256)
void scan_part_k(const float* __restrict__ delta, const float* __restrict__ uc,
                 const float* __restrict__ xdbc, const float* __restrict__ A_log,
                 float* __restrict__ Hpart, float* __restrict__ Sd,
                 int rev, int CB) {
    int NP = CB * DINNER;
    int idx = blockIdx.x * blockDim.x + threadIdx.x;
    if (idx >= NP * SCAN_C) return;
    int c = idx / NP, be = idx % NP;
    int b = be >> 9, e = be & (DINNER - 1);

    float A[DSTATE], h[DSTATE];
#pragma unroll
    for (int s = 0; s < DSTATE; s++) {
        A[s] = -__expf(A_log[e * DSTATE + s]);
        h[s] = 0.f;
    }
    float sd = 0.f;
    int tau1 = min((c + 1) * SCAN_TC, NVARS);
    for (int tau = c * SCAN_TC; tau < tau1; tau++) {
        int t = rev ? (NVARS - 1 - tau) : tau;
        size_t m = (size_t)b * NVARS + t;
        size_t me = m * DINNER + e;
        float d  = delta[me];
        float uv = uc[me];
        float du = d * uv;
        sd += d;
        const float* Bp = xdbc + m * 96 + DTRANK;
#pragma unroll
        for (int s = 0; s < DSTATE; s++)
            h[s] = __expf(d * A[s]) * h[s] + du * Bp[s];
    }
    Sd[(size_t)c * NP + be] = sd;
#pragma unroll
    for (int s = 0; s < DSTATE; s++)
        Hpart[((size_t)c * DSTATE + s) * NP + be] = h[s];
}

// Pass B: per be: carry across chunks; store each chunk's carry-in.
__global__ __launch_bounds__(256)
void scan_carry_k(const float* __restrict__ Hpart, const float* __restrict__ Sd,
                  const float* __restrict__ A_log, float* __restrict__ CarryIn,
                  int CB) {
    int NP = CB * DINNER;
    int be = blockIdx.x * blockDim.x + threadIdx.x;
    if (be >= NP) return;
    int e = be & (DINNER - 1);
    float A[DSTATE], carry[DSTATE];
#pragma unroll
    for (int s = 0; s < DSTATE; s++) {
        A[s] = -__expf(A_log[e * DSTATE + s]);
        carry[s] = 0.f;
    }
    for (int c = 0; c < SCAN_C; c++) {
        float sd = Sd[(size_t)c * NP + be];
#pragma unroll
        for (int s = 0; s < DSTATE; s++) {
            CarryIn[((size_t)c * DSTATE + s) * NP + be] = carry[s];
            float p = __expf(A[s] * sd);
            carry[s] = Hpart[((size_t)c * DSTATE + s) * NP + be] + p * carry[s];
        }
    }
}

// Pass C: per (chunk, be): rerun local scan seeded with carry-in, emit gated y.
// y may alias z (same-element read-before-write within one thread).
__global__ __launch_bounds__(256)
void scan_final_k(const float* __restrict__ delta, const float* __restrict__ uc,
                  const float* __restrict__ z, const float* __restrict__ xdbc,
                  const float* __restrict__ A_log, const float* __restrict__ Dp,
                  const float* __restrict__ CarryIn, float* __restrict__ y,
                  int rev, int CB) {
    int NP = CB * DINNER;
    int idx = blockIdx.x * blockDim.x + threadIdx.x;
    if (idx >= NP * SCAN_C) return;
    int c = idx / NP, be = idx % NP;
    int b = be >> 9, e = be & (DINNER - 1);

    float A[DSTATE], h[DSTATE];
#pragma unroll
    for (int s = 0; s < DSTATE; s++) {
        A[s] = -__expf(A_log[e * DSTATE + s]);
        h[s] = CarryIn[((size_t)c * DSTATE + s) * NP + be];
    }
    float Dv = Dp[e];
    int tau1 = min((c + 1) * SCAN_TC, NVARS);
    for (int tau = c * SCAN_TC; tau < tau1; tau++) {
        int t = rev ? (NVARS - 1 - tau) : tau;
        size_t m = (size_t)b * NVARS + t;
        size_t me = m * DINNER + e;
        float d  = delta[me];
        float uv = uc[me];
        float zz = z[me];
        float du = d * uv;
        const float* Bp = xdbc + m * 96 + DTRANK;
        const float* Cp = Bp + DSTATE;
        float accv = 0.f;
#pragma unroll
        for (int s = 0; s < DSTATE; s++) {
            h[s] = __expf(d * A[s]) * h[s] + du * Bp[s];
            accv += h[s] * Cp[s];
        }
        float sig = 1.f / (1.f + __expf(-zz));
        y[me] = (accv + uv * Dv) * (zz * sig);
    }
}

// ---------------------------------------------------------------- layernorm
__global__ __launch_bounds__(64)
void ln_k(const float* __restrict__ in1, const float* __restrict__ in2,
          const float* __restrict__ w, const float* __restrict__ b,
          float* __restrict__ out) {
    int row = blockIdx.x;
    int lane = threadIdx.x;
    const float* p1 = in1 + (size_t)row * DMODEL;
    const float* p2 = in2 ? in2 + (size_t)row * DMODEL : nullptr;
    float v[8];
#pragma unroll
    for (int i = 0; i < 8; i++) {
        int c = lane + i * 64;
        v[i] = p1[c];
        if (p2) v[i] += p2[c];
    }
    float s = 0.f;
#pragma unroll
    for (int i = 0; i < 8; i++) s += v[i];
#pragma unroll
    for (int off = 32; off >= 1; off >>= 1) s += __shfl_xor(s, off);
    float mean = s * (1.f / DMODEL);
    float q = 0.f;
#pragma unroll
    for (int i = 0; i < 8; i++) { float d = v[i] - mean; q += d * d; }
#pragma unroll
    for (int off = 32; off >= 1; off >>= 1) q += __shfl_xor(q, off);
    float rs = rsqrtf(q * (1.f / DMODEL) + 1e-5f);
    float* o = out + (size_t)row * DMODEL;
#pragma unroll
    for (int i = 0; i < 8; i++) {
        int c = lane + i * 64;
        o[c] = (v[i] - mean) * rs * w[c] + b[c];
    }
}

// ---------------------------------------------------------------- de-norm + transpose
__global__ void final_k(const float* __restrict__ dec, const float* __restrict__ meanb,
                        const float* __restrict__ stdb, float* __restrict__ out,
                        int b0, int CB) {
    int idx = blockIdx.x * blockDim.x + threadIdx.x;
    if (idx >= CB * LFUT * NVARS) return;
    int n = idx % NVARS;
    int r = idx / NVARS;
    int l = r % LFUT;
    int bl = r / LFUT;
    int tok = bl * NVARS + n;
    out[(size_t)((b0 + bl) * LFUT + l) * NVARS + n] =
        dec[(size_t)tok * LFUT + l] * stdb[tok] + meanb[tok];
}

// ---------------------------------------------------------------- launch
extern "C" void kernel_launch(void* const* d_in, const int* in_sizes, int n_in,
                              void* d_out, int out_size, void* d_ws, size_t ws_size,
                              hipStream_t stream) {
    const float* hist    = (const float*)d_in[0];
    const float* emb_w   = (const float*)d_in[1];
    const float* emb_b   = (const float*)d_in[2];
    const float* m_in_w  = (const float*)d_in[3];
    const float* m_conv_w= (const float*)d_in[4];
    const float* m_conv_b= (const float*)d_in[5];
    const float* m_x_w   = (const float*)d_in[6];
    const float* m_dt_w  = (const float*)d_in[7];
    const float* m_dt_b  = (const float*)d_in[8];
    const float* m_A_log = (const float*)d_in[9];
    const float* m_D     = (const float*)d_in[10];
    const float* m_out_w = (const float*)d_in[11];
    const float* ffn_w1  = (const float*)d_in[12];
    const float* ffn_b1  = (const float*)d_in[13];
    const float* ffn_w2  = (const float*)d_in[14];
    const float* ffn_b2  = (const float*)d_in[15];
    const float* norm1_w = (const float*)d_in[16];
    const float* norm1_b = (const float*)d_in[17];
    const float* norm2_w = (const float*)d_in[18];
    const float* norm2_b = (const float*)d_in[19];
    const float* normf_w = (const float*)d_in[20];
    const float* normf_b = (const float*)d_in[21];
    const float* proj_w  = (const float*)d_in[22];
    const float* proj_b  = (const float*)d_in[23];

    float* out = (float*)d_out;
    float* ws  = (float*)d_ws;

    // ---- adaptive batch chunking so the workspace footprint fits ws_size.
    // per-CB floats: 862*(5*512+2*96+2) + 512*SCAN_C*(2*32+1) = 2,906,428
    int CB = BATCH;
    while (CB > 1 && (size_t)CB * 2906428u * 4u > ws_size) CB >>= 1;
    const int R  = CB * NVARS;              // rows (tokens) per chunk
    const int NP = CB * DINNER;             // scan (b,e) pairs per chunk
    const size_t SB = (size_t)R * DMODEL;

    float* x     = ws;                 // activations
    float* acc   = ws + 1 * SB;        // fwd+rev out-proj accumulator
    float* ubuf  = ws + 2 * SB;        // u -> delta -> ffn mid (reused)
    float* zbuf  = ws + 3 * SB;        // z -> y (scan output, aliased)
    float* ucbuf = ws + 4 * SB;        // conv(u) -> ffn out (reused)
    float* xdbc  = ws + 5 * SB;        // [R,96] dt/B/C, later dec
    float* xin   = xdbc + (size_t)R * 96;   // [R,96] normalized history
    float* meanb = xin  + (size_t)R * 96;
    float* stdb  = meanb + R;
    float* Hpart = stdb + R;                        // [C][32][NP]
    float* CarryIn = Hpart + (size_t)SCAN_C * DSTATE * NP;  // [C][32][NP]
    float* Sd    = CarryIn + (size_t)SCAN_C * DSTATE * NP;  // [C][NP]

    auto gemm = [&](const float* A, int lda, const float* W, int ldw,
                    const float* bias, float* C, int ldc,
                    int M, int N, int K, int act, int accum) {
        dim3 grid((N + GBN - 1) / GBN, (M + GBM - 1) / GBM);
        gemm_k<<<grid, 256, 0, stream>>>(A, lda, W, ldw, bias, C, ldc, M, N, K, act, accum);
    };

    for (int b0 = 0; b0 < BATCH; b0 += CB) {
        meanstd_k<<<(R + 255) / 256, 256, 0, stream>>>(hist, xin, meanb, stdb, b0, CB);
        gemm(xin, LHIST, emb_w, DMODEL, emb_b, x, DMODEL, R, DMODEL, LHIST, 0, 0);

        for (int l = 0; l < 2; l++) {
            for (int dir = 0; dir < 2; dir++) {
                size_t p = (size_t)(l * 2 + dir);
                const float* inw  = m_in_w  + p * DMODEL * (2 * DINNER);
                const float* cw   = m_conv_w + p * DINNER * 2;
                const float* cb   = m_conv_b + p * DINNER;
                const float* xw   = m_x_w   + p * DINNER * 96;
                const float* dtw  = m_dt_w  + p * DTRANK * DINNER;
                const float* dtb  = m_dt_b  + p * DINNER;
                const float* alog = m_A_log + p * DINNER * DSTATE;
                const float* Dp   = m_D     + p * DINNER;
                const float* ow   = m_out_w + p * DINNER * DMODEL;

                // u, z = split(x @ in_w)
                gemm(x, DMODEL, inw,       2 * DINNER, nullptr, ubuf, DINNER, R, DINNER, DMODEL, 0, 0);
                gemm(x, DMODEL, inw + 512, 2 * DINNER, nullptr, zbuf, DINNER, R, DINNER, DMODEL, 0, 0);
                // causal depthwise conv + silu
                convsilu_k<<<(unsigned)(((size_t)R * DINNER + 255) / 256), 256, 0, stream>>>(
                    ubuf, cw, cb, ucbuf, dir, R);
                // dt/B/C projection
                gemm(ucbuf, DINNER, xw, 96, nullptr, xdbc, 96, R, 96, DINNER, 0, 0);
                // delta = softplus(dt @ dt_w + dt_b)   (into ubuf, u is dead)
                gemm(xdbc, 96, dtw, DINNER, dtb, ubuf, DINNER, R, DINNER, DTRANK, 2, 0);
                // chunked selective scan + gating (y aliases z)
                scan_part_k<<<(NP * SCAN_C + 255) / 256, 256, 0, stream>>>(
                    ubuf, ucbuf, xdbc, alog, Hpart, Sd, dir, CB);
                scan_carry_k<<<(NP + 255) / 256, 256, 0, stream>>>(
                    Hpart, Sd, alog, CarryIn, CB);
                scan_final_k<<<(NP * SCAN_C + 255) / 256, 256, 0, stream>>>(
                    ubuf, ucbuf, zbuf, xdbc, alog, Dp, CarryIn, zbuf, dir, CB);
                // acc (=)+= y @ out_w   (dir 0 overwrites, dir 1 accumulates)
                gemm(zbuf, DINNER, ow, DMODEL, nullptr, acc, DMODEL, R, DMODEL, DINNER, 0, dir);
            }
            // x = LN(x + fwd + rev)
            ln_k<<<R, 64, 0, stream>>>(acc, x, norm1_w + l * DMODEL, norm1_b + l * DMODEL, x);
            // FFN
            gemm(x, DMODEL, ffn_w1 + (size_t)l * DMODEL * DMODEL, DMODEL,
                 ffn_b1 + l * DMODEL, ubuf, DMODEL, R, DMODEL, DMODEL, 1, 0);
            gemm(ubuf, DMODEL, ffn_w2 + (size_t)l * DMODEL * DMODEL, DMODEL,
                 ffn_b2 + l * DMODEL, ucbuf, DMODEL, R, DMODEL, DMODEL, 0, 0);
            // x = LN(x + ffn)
            ln_k<<<R, 64, 0, stream>>>(x, ucbuf, norm2_w + l * DMODEL, norm2_b + l * DMODEL, x);
        }

        // final LN + projection + de-normalization
        ln_k<<<R, 64, 0, stream>>>(x, nullptr, normf_w, normf_b, x);
        gemm(x, DMODEL, proj_w, LFUT, proj_b, xdbc, LFUT, R, LFUT, DMODEL, 0, 0);
        final_k<<<(CB * LFUT * NVARS + 255) / 256, 256, 0, stream>>>(
            xdbc, meanb, stdb, out, b0, CB);
    }
}

// Round 4
// 4655.930 us; speedup vs baseline: 3.0063x; 1.5065x over previous
//
#include <hip/hip_runtime.h>
#include <math.h>

#define BATCH 32
#define LHIST 96
#define NVARS 862
#define LFUT  96
#define DMODEL 512
#define DINNER 512
#define DSTATE 32
#define DTRANK 32
#define SCAN_C 16
#define SCAN_TC ((NVARS + SCAN_C - 1) / SCAN_C)   // 54

typedef short short8 __attribute__((ext_vector_type(8)));
typedef float floatx4 __attribute__((ext_vector_type(4)));
typedef unsigned short ushort;

static __device__ __forceinline__ ushort f2b(float f) {
    unsigned u = __builtin_bit_cast(unsigned, f);
    unsigned r = (u + 0x7FFFu + ((u >> 16) & 1u)) >> 16;
    return (ushort)r;
}
static __device__ __forceinline__ float b2f(ushort h) {
    unsigned u = ((unsigned)h) << 16;
    return __builtin_bit_cast(float, u);
}

// ---------------------------------------------------------------- mean/std
// writes normalized history token-major as bf16 [R][96]
__global__ void meanstd_k(const float* __restrict__ hist, ushort* __restrict__ xinb,
                          float* __restrict__ meanb, float* __restrict__ stdb,
                          int b0, int CB) {
    int idx = blockIdx.x * blockDim.x + threadIdx.x;
    if (idx >= CB * NVARS) return;
    int b = b0 + idx / NVARS, n = idx % NVARS;
    const float* p = hist + (size_t)b * LHIST * NVARS + n;
    float s = 0.f;
    for (int l = 0; l < LHIST; l++) s += p[(size_t)l * NVARS];
    float mean = s * (1.f / LHIST);
    float v = 0.f;
    for (int l = 0; l < LHIST; l++) { float d = p[(size_t)l * NVARS] - mean; v += d * d; }
    v *= (1.f / LHIST);
    float sd = sqrtf(v + 1e-5f);
    float inv = 1.f / sd;
    meanb[idx] = mean;
    stdb[idx]  = sd;
    ushort* o = xinb + (size_t)idx * LHIST;
    for (int l = 0; l < LHIST; l++) o[l] = f2b((p[(size_t)l * NVARS] - mean) * inv);
}

// ---------------------------------------------------------------- weight cast+transpose
// Wt[n][k] = bf16(W[k][n])
__global__ void castT_k(const float* __restrict__ W, ushort* __restrict__ Wt,
                        int K, int N) {
    int idx = blockIdx.x * blockDim.x + threadIdx.x;
    if (idx >= K * N) return;
    int k = idx / N, n = idx % N;
    Wt[(size_t)n * K + k] = f2b(W[idx]);
}

// ---------------------------------------------------------------- bf16 MFMA GEMM
// C[M,N] = act(A[M,K]bf16 @ Bt[N,K]bf16^T + bias) (+C). 128x128x32 tile,
// 4 waves in 2x2, 4x4 mfma_f32_16x16x32_bf16 tiles per wave.
#define TBM 128
#define TBN 128
#define TBK 32

__global__ __launch_bounds__(256)
void bgemm_k(const ushort* __restrict__ A, int lda,
             const ushort* __restrict__ Bt, int ldb,
             const float* __restrict__ bias,
             float* __restrict__ C, int ldc,
             ushort* __restrict__ C2, int ldc2,
             int M, int N, int K, int act, int accum) {
    __shared__ ushort As[TBM][TBK];
    __shared__ ushort Bs[TBN][TBK];
    int tid = threadIdx.x;
    int gm0 = blockIdx.y * TBM, gn0 = blockIdx.x * TBN;
    int lane = tid & 63, w = tid >> 6;
    int wm = (w >> 1) * 64, wn = (w & 1) * 64;
    int col16 = lane & 15, quad = lane >> 4;

    floatx4 acc[4][4];
#pragma unroll
    for (int i = 0; i < 4; i++)
#pragma unroll
        for (int j = 0; j < 4; j++) acc[i][j] = (floatx4){0.f, 0.f, 0.f, 0.f};

    int srow = tid >> 2;            // 0..63
    int schunk = (tid & 3) * 8;     // k-element offset (0,8,16,24)

    for (int k0 = 0; k0 < K; k0 += TBK) {
        int ra0 = min(gm0 + srow, M - 1);
        int ra1 = min(gm0 + srow + 64, M - 1);
        short8 a0 = *(const short8*)(A + (size_t)ra0 * lda + k0 + schunk);
        short8 a1 = *(const short8*)(A + (size_t)ra1 * lda + k0 + schunk);
        int rb0 = min(gn0 + srow, N - 1);
        int rb1 = min(gn0 + srow + 64, N - 1);
        short8 b0 = *(const short8*)(Bt + (size_t)rb0 * ldb + k0 + schunk);
        short8 b1 = *(const short8*)(Bt + (size_t)rb1 * ldb + k0 + schunk);
        __syncthreads();
        *(short8*)&As[srow][schunk]      = a0;
        *(short8*)&As[srow + 64][schunk] = a1;
        *(short8*)&Bs[srow][schunk]      = b0;
        *(short8*)&Bs[srow + 64][schunk] = b1;
        __syncthreads();

        short8 af[4], bf[4];
#pragma unroll
        for (int mt = 0; mt < 4; mt++)
            af[mt] = *(const short8*)&As[wm + mt * 16 + col16][quad * 8];
#pragma unroll
        for (int nt = 0; nt < 4; nt++)
            bf[nt] = *(const short8*)&Bs[wn + nt * 16 + col16][quad * 8];
#pragma unroll
        for (int mt = 0; mt < 4; mt++)
#pragma unroll
            for (int nt = 0; nt < 4; nt++)
                acc[mt][nt] = __builtin_amdgcn_mfma_f32_16x16x32_bf16(
                    af[mt], bf[nt], acc[mt][nt], 0, 0, 0);
    }

    int rbase = gm0 + wm + quad * 4;
    int cbase = gn0 + wn + col16;
#pragma unroll
    for (int mt = 0; mt < 4; mt++) {
#pragma unroll
        for (int reg = 0; reg < 4; reg++) {
            int r = rbase + mt * 16 + reg;
            if (r >= M) continue;
#pragma unroll
            for (int nt = 0; nt < 4; nt++) {
                int c = cbase + nt * 16;
                if (c >= N) continue;
                float v = acc[mt][nt][reg];
                if (bias) v += bias[c];
                if (act == 1) v = fmaxf(v, 0.f);
                if (accum) v += C[(size_t)r * ldc + c];
                if (C)  C[(size_t)r * ldc + c] = v;
                if (C2) C2[(size_t)r * ldc2 + c] = f2b(v);
            }
        }
    }
}

// ---------------------------------------------------------------- fp32 GEMM (small N/K)
#define GBM 128
#define GBN 128
#define GBK 8

__global__ __launch_bounds__(256)
void gemm_k(const float* __restrict__ A, int lda,
            const float* __restrict__ W, int ldw,
            const float* __restrict__ bias,
            float* __restrict__ C, int ldc,
            int M, int N, int K, int act, int accum) {
    __shared__ float As[GBK][GBM];
    __shared__ float Ws[GBK][GBN];
    int tid = threadIdx.x;
    int gm0 = blockIdx.y * GBM, gn0 = blockIdx.x * GBN;
    int ty = tid >> 4, tx = tid & 15;

    float acc[8][8];
#pragma unroll
    for (int i = 0; i < 8; i++)
#pragma unroll
        for (int j = 0; j < 8; j++) acc[i][j] = 0.f;

    int lm = tid >> 1;
    int lk = (tid & 1) * 4;
    int wk = tid >> 5;
    int wn = (tid & 31) * 4;

    for (int k0 = 0; k0 < K; k0 += GBK) {
        float4 av = make_float4(0.f, 0.f, 0.f, 0.f);
        if (gm0 + lm < M)
            av = *(const float4*)(A + (size_t)(gm0 + lm) * lda + k0 + lk);
        float4 wv;
        int wc = gn0 + wn;
        const float* wp = W + (size_t)(k0 + wk) * ldw;
        if (wc + 3 < N) {
            wv = *(const float4*)(wp + wc);
        } else {
            wv.x = (wc + 0 < N) ? wp[wc + 0] : 0.f;
            wv.y = (wc + 1 < N) ? wp[wc + 1] : 0.f;
            wv.z = (wc + 2 < N) ? wp[wc + 2] : 0.f;
            wv.w = (wc + 3 < N) ? wp[wc + 3] : 0.f;
        }
        __syncthreads();
        As[lk + 0][lm] = av.x;
        As[lk + 1][lm] = av.y;
        As[lk + 2][lm] = av.z;
        As[lk + 3][lm] = av.w;
        *(float4*)&Ws[wk][wn] = wv;
        __syncthreads();
#pragma unroll
        for (int k = 0; k < GBK; k++) {
            float4 a0 = *(const float4*)&As[k][ty * 8];
            float4 a1 = *(const float4*)&As[k][ty * 8 + 4];
            float4 w0 = *(const float4*)&Ws[k][tx * 8];
            float4 w1 = *(const float4*)&Ws[k][tx * 8 + 4];
            float aa[8] = {a0.x, a0.y, a0.z, a0.w, a1.x, a1.y, a1.z, a1.w};
            float ww[8] = {w0.x, w0.y, w0.z, w0.w, w1.x, w1.y, w1.z, w1.w};
#pragma unroll
            for (int i = 0; i < 8; i++)
#pragma unroll
                for (int j = 0; j < 8; j++) acc[i][j] += aa[i] * ww[j];
        }
    }

#pragma unroll
    for (int i = 0; i < 8; i++) {
        int r = gm0 + ty * 8 + i;
        if (r >= M) continue;
        float* crow = C + (size_t)r * ldc;
#pragma unroll
        for (int j = 0; j < 8; j++) {
            int c = gn0 + tx * 8 + j;
            if (c >= N) continue;
            float v = acc[i][j];
            if (bias) v += bias[c];
            if (act == 1) v = fmaxf(v, 0.f);
            else if (act == 2) v = (v > 20.f) ? v : log1pf(expf(v));
            if (accum) v += crow[c];
            crow[c] = v;
        }
    }
}

// ---------------------------------------------------------------- conv+silu
// u lives in uz[:, 0:512] (stride 1024). Writes uc fp32 [R][512].
__global__ void convsilu_k(const float* __restrict__ uz, const float* __restrict__ cw,
                           const float* __restrict__ cb, float* __restrict__ uc,
                           int rev, int R) {
    size_t idx = (size_t)blockIdx.x * blockDim.x + threadIdx.x;
    if (idx >= (size_t)R * DINNER) return;
    int e = (int)(idx & (DINNER - 1));
    int m = (int)(idx >> 9);
    int t = m % NVARS;
    size_t src = (size_t)m * 1024 + e;
    float cur = uz[src];
    float other = 0.f;
    if (!rev) { if (t > 0)          other = uz[src - 1024]; }
    else      { if (t < NVARS - 1)  other = uz[src + 1024]; }
    float v = cw[e * 2] * other + cw[e * 2 + 1] * cur + cb[e];
    float sig = 1.f / (1.f + __expf(-v));
    uc[idx] = v * sig;
}

// ---------------------------------------------------------------- chunked scan
// delta lives in uz[:, 0:512], z in uz[:, 512:1024] (stride 1024).

// Pass A: local scan from h=0 -> Hpart[c][s][be], Sd[c][be]
__global__ __launch_bounds__(256)
void scan_part_k(const float* __restrict__ uz, const float* __restrict__ uc,
                 const float* __restrict__ xdbc, const float* __restrict__ A_log,
                 float* __restrict__ Hpart, float* __restrict__ Sd,
                 int rev, int CB) {
    int NP = CB * DINNER;
    int idx = blockIdx.x * blockDim.x + threadIdx.x;
    if (idx >= NP * SCAN_C) return;
    int c = idx / NP, be = idx % NP;
    int b = be >> 9, e = be & (DINNER - 1);

    float A[DSTATE], h[DSTATE];
#pragma unroll
    for (int s = 0; s < DSTATE; s++) {
        A[s] = -__expf(A_log[e * DSTATE + s]);
        h[s] = 0.f;
    }
    float sd = 0.f;
    int tau1 = min((c + 1) * SCAN_TC, NVARS);
    for (int tau = c * SCAN_TC; tau < tau1; tau++) {
        int t = rev ? (NVARS - 1 - tau) : tau;
        size_t m = (size_t)b * NVARS + t;
        float d  = uz[m * 1024 + e];
        float uv = uc[m * DINNER + e];
        float du = d * uv;
        sd += d;
        const float* Bp = xdbc + m * 96 + DTRANK;
#pragma unroll
        for (int s = 0; s < DSTATE; s++)
            h[s] = __expf(d * A[s]) * h[s] + du * Bp[s];
    }
    Sd[(size_t)c * NP + be] = sd;
#pragma unroll
    for (int s = 0; s < DSTATE; s++)
        Hpart[((size_t)c * DSTATE + s) * NP + be] = h[s];
}

// Pass B: carry across chunks, overwriting Hpart with each chunk's carry-IN.
__global__ __launch_bounds__(256)
void scan_carry_k(float* __restrict__ Hpart, const float* __restrict__ Sd,
                  const float* __restrict__ A_log, int CB) {
    int NP = CB * DINNER;
    int be = blockIdx.x * blockDim.x + threadIdx.x;
    if (be >= NP) return;
    int e = be & (DINNER - 1);
    float A[DSTATE], carry[DSTATE];
#pragma unroll
    for (int s = 0; s < DSTATE; s++) {
        A[s] = -__expf(A_log[e * DSTATE + s]);
        carry[s] = 0.f;
    }
    for (int c = 0; c < SCAN_C; c++) {
        float sd = Sd[(size_t)c * NP + be];
#pragma unroll
        for (int s = 0; s < DSTATE; s++) {
            size_t off = ((size_t)c * DSTATE + s) * NP + be;
            float hp = Hpart[off];
            Hpart[off] = carry[s];
            carry[s] = hp + __expf(A[s] * sd) * carry[s];
        }
    }
}

// Pass C: rerun local scan seeded with carry-in; emit gated y as bf16.
__global__ __launch_bounds__(256)
void scan_final_k(const float* __restrict__ uz, const float* __restrict__ uc,
                  const float* __restrict__ xdbc, const float* __restrict__ A_log,
                  const float* __restrict__ Dp, const float* __restrict__ CarryIn,
                  ushort* __restrict__ yb, int rev, int CB) {
    int NP = CB * DINNER;
    int idx = blockIdx.x * blockDim.x + threadIdx.x;
    if (idx >= NP * SCAN_C) return;
    int c = idx / NP, be = idx % NP;
    int b = be >> 9, e = be & (DINNER - 1);

    float A[DSTATE], h[DSTATE];
#pragma unroll
    for (int s = 0; s < DSTATE; s++) {
        A[s] = -__expf(A_log[e * DSTATE + s]);
        h[s] = CarryIn[((size_t)c * DSTATE + s) * NP + be];
    }
    float Dv = Dp[e];
    int tau1 = min((c + 1) * SCAN_TC, NVARS);
    for (int tau = c * SCAN_TC; tau < tau1; tau++) {
        int t = rev ? (NVARS - 1 - tau) : tau;
        size_t m = (size_t)b * NVARS + t;
        float d  = uz[m * 1024 + e];
        float zz = uz[m * 1024 + 512 + e];
        float uv = uc[m * DINNER + e];
        float du = d * uv;
        const float* Bp = xdbc + m * 96 + DTRANK;
        const float* Cp = Bp + DSTATE;
        float accv = 0.f;
#pragma unroll
        for (int s = 0; s < DSTATE; s++) {
            h[s] = __expf(d * A[s]) * h[s] + du * Bp[s];
            accv += h[s] * Cp[s];
        }
        float sig = 1.f / (1.f + __expf(-zz));
        yb[m * DINNER + e] = f2b((accv + uv * Dv) * (zz * sig));
    }
}

// ---------------------------------------------------------------- layernorm
// out fp32 (opt) + bf16 (opt)
__global__ __launch_bounds__(64)
void ln_k(const float* __restrict__ in1, const float* __restrict__ in2,
          const float* __restrict__ w, const float* __restrict__ b,
          float* __restrict__ out, ushort* __restrict__ outb) {
    int row = blockIdx.x;
    int lane = threadIdx.x;
    const float* p1 = in1 + (size_t)row * DMODEL;
    const float* p2 = in2 ? in2 + (size_t)row * DMODEL : nullptr;
    float v[8];
#pragma unroll
    for (int i = 0; i < 8; i++) {
        int c = lane + i * 64;
        v[i] = p1[c];
        if (p2) v[i] += p2[c];
    }
    float s = 0.f;
#pragma unroll
    for (int i = 0; i < 8; i++) s += v[i];
#pragma unroll
    for (int off = 32; off >= 1; off >>= 1) s += __shfl_xor(s, off);
    float mean = s * (1.f / DMODEL);
    float q = 0.f;
#pragma unroll
    for (int i = 0; i < 8; i++) { float d = v[i] - mean; q += d * d; }
#pragma unroll
    for (int off = 32; off >= 1; off >>= 1) q += __shfl_xor(q, off);
    float rs = rsqrtf(q * (1.f / DMODEL) + 1e-5f);
#pragma unroll
    for (int i = 0; i < 8; i++) {
        int c = lane + i * 64;
        float o = (v[i] - mean) * rs * w[c] + b[c];
        if (out)  out[(size_t)row * DMODEL + c] = o;
        if (outb) outb[(size_t)row * DMODEL + c] = f2b(o);
    }
}

// ---------------------------------------------------------------- de-norm + transpose
__global__ void final_k(const float* __restrict__ dec, const float* __restrict__ meanb,
                        const float* __restrict__ stdb, float* __restrict__ out,
                        int b0, int CB) {
    int idx = blockIdx.x * blockDim.x + threadIdx.x;
    if (idx >= CB * LFUT * NVARS) return;
    int n = idx % NVARS;
    int r = idx / NVARS;
    int l = r % LFUT;
    int bl = r / LFUT;
    int tok = bl * NVARS + n;
    out[(size_t)((b0 + bl) * LFUT + l) * NVARS + n] =
        dec[(size_t)tok * LFUT + l] * stdb[tok] + meanb[tok];
}

// ---------------------------------------------------------------- launch
extern "C" void kernel_launch(void* const* d_in, const int* in_sizes, int n_in,
                              void* d_out, int out_size, void* d_ws, size_t ws_size,
                              hipStream_t stream) {
    const float* hist    = (const float*)d_in[0];
    const float* emb_w   = (const float*)d_in[1];
    const float* emb_b   = (const float*)d_in[2];
    const float* m_in_w  = (const float*)d_in[3];
    const float* m_conv_w= (const float*)d_in[4];
    const float* m_conv_b= (const float*)d_in[5];
    const float* m_x_w   = (const float*)d_in[6];
    const float* m_dt_w  = (const float*)d_in[7];
    const float* m_dt_b  = (const float*)d_in[8];
    const float* m_A_log = (const float*)d_in[9];
    const float* m_D     = (const float*)d_in[10];
    const float* m_out_w = (const float*)d_in[11];
    const float* ffn_w1  = (const float*)d_in[12];
    const float* ffn_b1  = (const float*)d_in[13];
    const float* ffn_w2  = (const float*)d_in[14];
    const float* ffn_b2  = (const float*)d_in[15];
    const float* norm1_w = (const float*)d_in[16];
    const float* norm1_b = (const float*)d_in[17];
    const float* norm2_w = (const float*)d_in[18];
    const float* norm2_b = (const float*)d_in[19];
    const float* normf_w = (const float*)d_in[20];
    const float* normf_b = (const float*)d_in[21];
    const float* proj_w  = (const float*)d_in[22];
    const float* proj_b  = (const float*)d_in[23];

    float* out = (float*)d_out;
    float* ws  = (float*)d_ws;

    // per-chunk bytes (CB=1): fp32 uz/x/acc/uc/xdbc/mean/std + scan, bf16 xb/ybmid/xinb
    const size_t perCB = (size_t)862 * 2658 * 4 + (size_t)SCAN_C * 512 * 33 * 4
                       + (size_t)862 * 1120 * 2;
    const size_t WTS_ELEMS = 4u * 512 * 1024 + 4u * 512 * 512 + 4u * 512 * 512 + 96u * 512;
    const size_t wbytes = WTS_ELEMS * 2 + 256;
    int CB = BATCH;
    while (CB > 1 && (size_t)CB * perCB + wbytes > ws_size) CB >>= 1;
    const int R  = CB * NVARS;
    const int NP = CB * DINNER;

    float* uz    = ws;                                   // [R][1024]
    float* x     = uz + (size_t)R * 1024;                // [R][512]
    float* accb  = x + (size_t)R * 512;                  // [R][512]
    float* uc    = accb + (size_t)R * 512;               // [R][512]
    float* xdbc  = uc + (size_t)R * 512;                 // [R][96]
    float* meanb = xdbc + (size_t)R * 96;
    float* stdb  = meanb + R;
    float* Hpart = stdb + R;                             // [C][32][NP]
    float* Sd    = Hpart + (size_t)SCAN_C * DSTATE * NP; // [C][NP]
    ushort* xb    = (ushort*)(Sd + (size_t)SCAN_C * NP); // [R][512] bf16
    ushort* ybmid = xb + (size_t)R * 512;                // [R][512] bf16 (y / ffn-mid)
    ushort* xinb  = ybmid + (size_t)R * 512;             // [R][96]  bf16
    ushort* wts   = xinb + (size_t)R * 96;               // bf16 weights

    ushort* inw_t[4], *outw_t[4], *f1_t[2], *f2_t[2], *emb_t;
    {
        ushort* p = wts;
        for (int i = 0; i < 4; i++) { inw_t[i]  = p; p += (size_t)1024 * 512; }
        for (int i = 0; i < 4; i++) { outw_t[i] = p; p += (size_t)512 * 512; }
        for (int i = 0; i < 2; i++) { f1_t[i]   = p; p += (size_t)512 * 512; }
        for (int i = 0; i < 2; i++) { f2_t[i]   = p; p += (size_t)512 * 512; }
        emb_t = p;
    }

    // cast+transpose all weights once per launch
    for (int i = 0; i < 4; i++)
        castT_k<<<(512 * 1024 + 255) / 256, 256, 0, stream>>>(
            m_in_w + (size_t)i * 512 * 1024, inw_t[i], 512, 1024);
    for (int i = 0; i < 4; i++)
        castT_k<<<(512 * 512 + 255) / 256, 256, 0, stream>>>(
            m_out_w + (size_t)i * 512 * 512, outw_t[i], 512, 512);
    for (int i = 0; i < 2; i++)
        castT_k<<<(512 * 512 + 255) / 256, 256, 0, stream>>>(
            ffn_w1 + (size_t)i * 512 * 512, f1_t[i], 512, 512);
    for (int i = 0; i < 2; i++)
        castT_k<<<(512 * 512 + 255) / 256, 256, 0, stream>>>(
            ffn_w2 + (size_t)i * 512 * 512, f2_t[i], 512, 512);
    castT_k<<<(96 * 512 + 255) / 256, 256, 0, stream>>>(emb_w, emb_t, 96, 512);

    auto bgemm = [&](const ushort* A, int lda, const ushort* Bt, int ldb,
                     const float* bias, float* C, int ldc, ushort* C2, int ldc2,
                     int M, int N, int K, int act, int accum) {
        dim3 grid((N + TBN - 1) / TBN, (M + TBM - 1) / TBM);
        bgemm_k<<<grid, 256, 0, stream>>>(A, lda, Bt, ldb, bias, C, ldc, C2, ldc2,
                                          M, N, K, act, accum);
    };
    auto gemm = [&](const float* A, int lda, const float* W, int ldw,
                    const float* bias, float* C, int ldc,
                    int M, int N, int K, int act, int accum) {
        dim3 grid((N + GBN - 1) / GBN, (M + GBM - 1) / GBM);
        gemm_k<<<grid, 256, 0, stream>>>(A, lda, W, ldw, bias, C, ldc, M, N, K, act, accum);
    };

    for (int b0 = 0; b0 < BATCH; b0 += CB) {
        meanstd_k<<<(R + 255) / 256, 256, 0, stream>>>(hist, xinb, meanb, stdb, b0, CB);
        // x = xin @ emb_w + emb_b   (fp32 + bf16 outputs)
        bgemm(xinb, 96, emb_t, 96, emb_b, x, 512, xb, 512, R, 512, 96, 0, 0);

        for (int l = 0; l < 2; l++) {
            for (int dir = 0; dir < 2; dir++) {
                int p = l * 2 + dir;
                const float* cw   = m_conv_w + (size_t)p * DINNER * 2;
                const float* cb   = m_conv_b + (size_t)p * DINNER;
                const float* xw   = m_x_w   + (size_t)p * DINNER * 96;
                const float* dtw  = m_dt_w  + (size_t)p * DTRANK * DINNER;
                const float* dtb  = m_dt_b  + (size_t)p * DINNER;
                const float* alog = m_A_log + (size_t)p * DINNER * DSTATE;
                const float* Dp   = m_D     + (size_t)p * DINNER;

                // uz = x @ in_w   [R][1024]
                bgemm(xb, 512, inw_t[p], 512, nullptr, uz, 1024, nullptr, 0,
                      R, 1024, 512, 0, 0);
                // uc = silu(conv(u))
                convsilu_k<<<(unsigned)(((size_t)R * DINNER + 255) / 256), 256, 0, stream>>>(
                    uz, cw, cb, uc, dir, R);
                // xdbc = uc @ x_w  [R][96]  (fp32)
                gemm(uc, DINNER, xw, 96, nullptr, xdbc, 96, R, 96, DINNER, 0, 0);
                // delta = softplus(dt @ dt_w + dt_b) -> uz[:, 0:512] (u is dead)
                gemm(xdbc, 96, dtw, DINNER, dtb, uz, 1024, R, DINNER, DTRANK, 2, 0);
                // chunked scan (y -> bf16 ybmid)
                scan_part_k<<<(NP * SCAN_C + 255) / 256, 256, 0, stream>>>(
                    uz, uc, xdbc, alog, Hpart, Sd, dir, CB);
                scan_carry_k<<<(NP + 255) / 256, 256, 0, stream>>>(Hpart, Sd, alog, CB);
                scan_final_k<<<(NP * SCAN_C + 255) / 256, 256, 0, stream>>>(
                    uz, uc, xdbc, alog, Dp, Hpart, ybmid, dir, CB);
                // acc (=)+= y @ out_w
                bgemm(ybmid, 512, outw_t[p], 512, nullptr, accb, 512, nullptr, 0,
                      R, 512, 512, 0, dir);
            }
            // x = LN(x + fwd + rev)  (fp32 + bf16)
            ln_k<<<R, 64, 0, stream>>>(accb, x, norm1_w + l * DMODEL, norm1_b + l * DMODEL,
                                       x, xb);
            // FFN: mid = relu(x @ w1 + b1) (bf16 only) ; uc = mid @ w2 + b2 (fp32)
            bgemm(xb, 512, f1_t[l], 512, ffn_b1 + l * DMODEL, nullptr, 0, ybmid, 512,
                  R, 512, 512, 1, 0);
            bgemm(ybmid, 512, f2_t[l], 512, ffn_b2 + l * DMODEL, uc, 512, nullptr, 0,
                  R, 512, 512, 0, 0);
            // x = LN(x + ffn)
            ln_k<<<R, 64, 0, stream>>>(x, uc, norm2_w + l * DMODEL, norm2_b + l * DMODEL,
                                       x, xb);
        }

        // final LN + projection + de-normalization
        ln_k<<<R, 64, 0, stream>>>(x, nullptr, normf_w, normf_b, x, nullptr);
        gemm(x, DMODEL, proj_w, LFUT, proj_b, xdbc, LFUT, R, LFUT, DMODEL, 0, 0);
        final_k<<<(CB * LFUT * NVARS + 255) / 256, 256, 0, stream>>>(
            xdbc, meanb, stdb, out, b0, CB);
    }
}

// Round 6
// 3121.391 us; speedup vs baseline: 4.4843x; 1.4916x over previous
//
#include <hip/hip_runtime.h>
#include <math.h>

#define BATCH 32
#define LHIST 96
#define NVARS 862
#define LFUT  96
#define DMODEL 512
#define DINNER 512
#define DSTATE 32
#define DTRANK 32
#define SCAN_C 32
#define SCAN_TC ((NVARS + SCAN_C - 1) / SCAN_C)   // 27

typedef short short8 __attribute__((ext_vector_type(8)));
typedef float floatx4 __attribute__((ext_vector_type(4)));
typedef unsigned short ushort;

#define LOG2E 1.44269504088896f

static __device__ __forceinline__ ushort f2b(float f) {
    unsigned u = __builtin_bit_cast(unsigned, f);
    unsigned r = (u + 0x7FFFu + ((u >> 16) & 1u)) >> 16;
    return (ushort)r;
}
static __device__ __forceinline__ float b2f(ushort h) {
    unsigned u = ((unsigned)h) << 16;
    return __builtin_bit_cast(float, u);
}

// ---------------------------------------------------------------- mean/std
__global__ void meanstd_k(const float* __restrict__ hist, ushort* __restrict__ xinb,
                          float* __restrict__ meanb, float* __restrict__ stdb,
                          int b0, int CB) {
    int idx = blockIdx.x * blockDim.x + threadIdx.x;
    if (idx >= CB * NVARS) return;
    int b = b0 + idx / NVARS, n = idx % NVARS;
    const float* p = hist + (size_t)b * LHIST * NVARS + n;
    float s = 0.f;
    for (int l = 0; l < LHIST; l++) s += p[(size_t)l * NVARS];
    float mean = s * (1.f / LHIST);
    float v = 0.f;
    for (int l = 0; l < LHIST; l++) { float d = p[(size_t)l * NVARS] - mean; v += d * d; }
    v *= (1.f / LHIST);
    float sd = sqrtf(v + 1e-5f);
    float inv = 1.f / sd;
    meanb[idx] = mean;
    stdb[idx]  = sd;
    ushort* o = xinb + (size_t)idx * LHIST;
    for (int l = 0; l < LHIST; l++) o[l] = f2b((p[(size_t)l * NVARS] - mean) * inv);
}

// ---------------------------------------------------------------- weight cast+transpose
// Wt[n][k] = bf16(W[k][n]);  W is [K][N]
__global__ void castT_k(const float* __restrict__ W, ushort* __restrict__ Wt,
                        int K, int N) {
    int idx = blockIdx.x * blockDim.x + threadIdx.x;
    if (idx >= K * N) return;
    int k = idx / N, n = idx % N;
    Wt[(size_t)n * K + k] = f2b(W[idx]);
}

// ---------------------------------------------------------------- bf16 MFMA GEMM
// C[M,N] = act(A[M,K]bf16 @ Bt[N,K]^T + bias) (+C). 128x128x32 tile,
// act: 0 none, 1 relu, 2 softplus.
#define TBM 128
#define TBN 128
#define TBK 32

__global__ __launch_bounds__(256)
void bgemm_k(const ushort* __restrict__ A, int lda,
             const ushort* __restrict__ Bt, int ldb,
             const float* __restrict__ bias,
             float* __restrict__ C, int ldc,
             ushort* __restrict__ C2, int ldc2,
             int M, int N, int K, int act, int accum) {
    __shared__ ushort As[TBM][TBK];
    __shared__ ushort Bs[TBN][TBK];
    int tid = threadIdx.x;
    int gm0 = blockIdx.y * TBM, gn0 = blockIdx.x * TBN;
    int lane = tid & 63, w = tid >> 6;
    int wm = (w >> 1) * 64, wn = (w & 1) * 64;
    int col16 = lane & 15, quad = lane >> 4;

    floatx4 acc[4][4];
#pragma unroll
    for (int i = 0; i < 4; i++)
#pragma unroll
        for (int j = 0; j < 4; j++) acc[i][j] = (floatx4){0.f, 0.f, 0.f, 0.f};

    int srow = tid >> 2;
    int schunk = (tid & 3) * 8;

    for (int k0 = 0; k0 < K; k0 += TBK) {
        int ra0 = min(gm0 + srow, M - 1);
        int ra1 = min(gm0 + srow + 64, M - 1);
        short8 a0 = *(const short8*)(A + (size_t)ra0 * lda + k0 + schunk);
        short8 a1 = *(const short8*)(A + (size_t)ra1 * lda + k0 + schunk);
        int rb0 = min(gn0 + srow, N - 1);
        int rb1 = min(gn0 + srow + 64, N - 1);
        short8 b0 = *(const short8*)(Bt + (size_t)rb0 * ldb + k0 + schunk);
        short8 b1 = *(const short8*)(Bt + (size_t)rb1 * ldb + k0 + schunk);
        __syncthreads();
        *(short8*)&As[srow][schunk]      = a0;
        *(short8*)&As[srow + 64][schunk] = a1;
        *(short8*)&Bs[srow][schunk]      = b0;
        *(short8*)&Bs[srow + 64][schunk] = b1;
        __syncthreads();

        short8 af[4], bf[4];
#pragma unroll
        for (int mt = 0; mt < 4; mt++)
            af[mt] = *(const short8*)&As[wm + mt * 16 + col16][quad * 8];
#pragma unroll
        for (int nt = 0; nt < 4; nt++)
            bf[nt] = *(const short8*)&Bs[wn + nt * 16 + col16][quad * 8];
#pragma unroll
        for (int mt = 0; mt < 4; mt++)
#pragma unroll
            for (int nt = 0; nt < 4; nt++)
                acc[mt][nt] = __builtin_amdgcn_mfma_f32_16x16x32_bf16(
                    af[mt], bf[nt], acc[mt][nt], 0, 0, 0);
    }

    int rbase = gm0 + wm + quad * 4;
    int cbase = gn0 + wn + col16;
#pragma unroll
    for (int mt = 0; mt < 4; mt++) {
#pragma unroll
        for (int reg = 0; reg < 4; reg++) {
            int r = rbase + mt * 16 + reg;
            if (r >= M) continue;
#pragma unroll
            for (int nt = 0; nt < 4; nt++) {
                int c = cbase + nt * 16;
                if (c >= N) continue;
                float v = acc[mt][nt][reg];
                if (bias) v += bias[c];
                if (act == 1) v = fmaxf(v, 0.f);
                else if (act == 2) v = (v > 20.f) ? v : log1pf(expf(v));
                if (accum) v += C[(size_t)r * ldc + c];
                if (C)  C[(size_t)r * ldc + c] = v;
                if (C2) C2[(size_t)r * ldc2 + c] = f2b(v);
            }
        }
    }
}

// ---------------------------------------------------------------- conv+silu
// u lives in uz[:, 0:512] (stride 1024). Writes bf16 ucb [R][512].
__global__ void convsilu_k(const float* __restrict__ uz, const float* __restrict__ cw,
                           const float* __restrict__ cb, ushort* __restrict__ ucb,
                           int rev, int R) {
    size_t idx = (size_t)blockIdx.x * blockDim.x + threadIdx.x;
    if (idx >= (size_t)R * DINNER) return;
    int e = (int)(idx & (DINNER - 1));
    int m = (int)(idx >> 9);
    int t = m % NVARS;
    size_t src = (size_t)m * 1024 + e;
    float cur = uz[src];
    float other = 0.f;
    if (!rev) { if (t > 0)          other = uz[src - 1024]; }
    else      { if (t < NVARS - 1)  other = uz[src + 1024]; }
    float v = cw[e * 2] * other + cw[e * 2 + 1] * cur + cb[e];
    float sig = 1.f / (1.f + __expf(-v));
    ucb[idx] = f2b(v * sig);
}

// ---------------------------------------------------------------- chunked scan
// delta in uz[:,0:512], z in uz[:,512:1024], u(bf16) in ucb, B/C(fp32) in xdbc.
// A_log is log(1..32) by construction -> A[s] = -(s+1): exp(d*A[s]) = q^(s+1),
// q = exp(-d). Runtime-checked; slow path uses exp2f with premultiplied log2e.

// Pass A: local scan from h=0 -> Hpart[c][s][be], Sd[c][be]
__global__ __launch_bounds__(256)
void scan_part_k(const float* __restrict__ uz, const ushort* __restrict__ ucb,
                 const float* __restrict__ xdbc, const float* __restrict__ A_log,
                 float* __restrict__ Hpart, float* __restrict__ Sd,
                 int rev, int CB) {
    int NP = CB * DINNER;
    int idx = blockIdx.x * blockDim.x + threadIdx.x;
    if (idx >= NP * SCAN_C) return;
    int c = idx / NP, be = idx % NP;
    int b = be >> 9, e = be & (DINNER - 1);

    float A[DSTATE], h[DSTATE];
    bool fastA = true;
#pragma unroll
    for (int s = 0; s < DSTATE; s++) {
        float a = -__expf(A_log[e * DSTATE + s]);
        fastA = fastA && (fabsf(a + (float)(s + 1)) < 1e-3f * (s + 1));
        A[s] = a * LOG2E;
        h[s] = 0.f;
    }
    float sd = 0.f;
    int tau1 = min((c + 1) * SCAN_TC, NVARS);
    if (fastA) {
        for (int tau = c * SCAN_TC; tau < tau1; tau++) {
            int t = rev ? (NVARS - 1 - tau) : tau;
            size_t m = (size_t)b * NVARS + t;
            float d  = uz[m * 1024 + e];
            float uv = b2f(ucb[m * DINNER + e]);
            float du = d * uv;
            sd += d;
            const float* Bp = xdbc + m * 96 + DTRANK;
            float q = __expf(-d), pw = q;
#pragma unroll
            for (int s = 0; s < DSTATE; s++) {
                h[s] = pw * h[s] + du * Bp[s];
                pw *= q;
            }
        }
    } else {
        for (int tau = c * SCAN_TC; tau < tau1; tau++) {
            int t = rev ? (NVARS - 1 - tau) : tau;
            size_t m = (size_t)b * NVARS + t;
            float d  = uz[m * 1024 + e];
            float uv = b2f(ucb[m * DINNER + e]);
            float du = d * uv;
            sd += d;
            const float* Bp = xdbc + m * 96 + DTRANK;
#pragma unroll
            for (int s = 0; s < DSTATE; s++)
                h[s] = exp2f(d * A[s]) * h[s] + du * Bp[s];
        }
    }
    Sd[(size_t)c * NP + be] = sd;
#pragma unroll
    for (int s = 0; s < DSTATE; s++)
        Hpart[((size_t)c * DSTATE + s) * NP + be] = h[s];
}

// Pass B: thread per (s, be); carry across chunks; Hpart -> carry-in (in place).
__global__ __launch_bounds__(256)
void scan_carry_k(float* __restrict__ Hpart, const float* __restrict__ Sd,
                  const float* __restrict__ A_log, int CB) {
    int NP = CB * DINNER;
    int idx = blockIdx.x * blockDim.x + threadIdx.x;
    if (idx >= NP * DSTATE) return;
    int s = idx / NP, be = idx % NP;
    int e = be & (DINNER - 1);
    float a2 = -__expf(A_log[e * DSTATE + s]) * LOG2E;
    float carry = 0.f;
    for (int c = 0; c < SCAN_C; c++) {
        float sd = Sd[(size_t)c * NP + be];
        size_t off = ((size_t)c * DSTATE + s) * NP + be;
        float hp = Hpart[off];
        Hpart[off] = carry;
        carry = hp + exp2f(a2 * sd) * carry;
    }
}

// Pass C: rerun local scan seeded with carry-in; emit gated y as bf16.
__global__ __launch_bounds__(256)
void scan_final_k(const float* __restrict__ uz, const ushort* __restrict__ ucb,
                  const float* __restrict__ xdbc, const float* __restrict__ A_log,
                  const float* __restrict__ Dp, const float* __restrict__ CarryIn,
                  ushort* __restrict__ yb, int rev, int CB) {
    int NP = CB * DINNER;
    int idx = blockIdx.x * blockDim.x + threadIdx.x;
    if (idx >= NP * SCAN_C) return;
    int c = idx / NP, be = idx % NP;
    int b = be >> 9, e = be & (DINNER - 1);

    float A[DSTATE], h[DSTATE];
    bool fastA = true;
#pragma unroll
    for (int s = 0; s < DSTATE; s++) {
        float a = -__expf(A_log[e * DSTATE + s]);
        fastA = fastA && (fabsf(a + (float)(s + 1)) < 1e-3f * (s + 1));
        A[s] = a * LOG2E;
        h[s] = CarryIn[((size_t)c * DSTATE + s) * NP + be];
    }
    float Dv = Dp[e];
    int tau1 = min((c + 1) * SCAN_TC, NVARS);
    if (fastA) {
        for (int tau = c * SCAN_TC; tau < tau1; tau++) {
            int t = rev ? (NVARS - 1 - tau) : tau;
            size_t m = (size_t)b * NVARS + t;
            float d  = uz[m * 1024 + e];
            float zz = uz[m * 1024 + 512 + e];
            float uv = b2f(ucb[m * DINNER + e]);
            float du = d * uv;
            const float* Bp = xdbc + m * 96 + DTRANK;
            const float* Cp = Bp + DSTATE;
            float q = __expf(-d), pw = q;
            float accv = 0.f;
#pragma unroll
            for (int s = 0; s < DSTATE; s++) {
                h[s] = pw * h[s] + du * Bp[s];
                accv += h[s] * Cp[s];
                pw *= q;
            }
            float sig = 1.f / (1.f + __expf(-zz));
            yb[m * DINNER + e] = f2b((accv + uv * Dv) * (zz * sig));
        }
    } else {
        for (int tau = c * SCAN_TC; tau < tau1; tau++) {
            int t = rev ? (NVARS - 1 - tau) : tau;
            size_t m = (size_t)b * NVARS + t;
            float d  = uz[m * 1024 + e];
            float zz = uz[m * 1024 + 512 + e];
            float uv = b2f(ucb[m * DINNER + e]);
            float du = d * uv;
            const float* Bp = xdbc + m * 96 + DTRANK;
            const float* Cp = Bp + DSTATE;
            float accv = 0.f;
#pragma unroll
            for (int s = 0; s < DSTATE; s++) {
                h[s] = exp2f(d * A[s]) * h[s] + du * Bp[s];
                accv += h[s] * Cp[s];
            }
            float sig = 1.f / (1.f + __expf(-zz));
            yb[m * DINNER + e] = f2b((accv + uv * Dv) * (zz * sig));
        }
    }
}

// ---------------------------------------------------------------- layernorm
__global__ __launch_bounds__(64)
void ln_k(const float* __restrict__ in1, const float* __restrict__ in2,
          const float* __restrict__ w, const float* __restrict__ b,
          float* __restrict__ out, ushort* __restrict__ outb) {
    int row = blockIdx.x;
    int lane = threadIdx.x;
    const float* p1 = in1 + (size_t)row * DMODEL;
    const float* p2 = in2 ? in2 + (size_t)row * DMODEL : nullptr;
    float v[8];
#pragma unroll
    for (int i = 0; i < 8; i++) {
        int c = lane + i * 64;
        v[i] = p1[c];
        if (p2) v[i] += p2[c];
    }
    float s = 0.f;
#pragma unroll
    for (int i = 0; i < 8; i++) s += v[i];
#pragma unroll
    for (int off = 32; off >= 1; off >>= 1) s += __shfl_xor(s, off);
    float mean = s * (1.f / DMODEL);
    float q = 0.f;
#pragma unroll
    for (int i = 0; i < 8; i++) { float d = v[i] - mean; q += d * d; }
#pragma unroll
    for (int off = 32; off >= 1; off >>= 1) q += __shfl_xor(q, off);
    float rs = rsqrtf(q * (1.f / DMODEL) + 1e-5f);
#pragma unroll
    for (int i = 0; i < 8; i++) {
        int c = lane + i * 64;
        float o = (v[i] - mean) * rs * w[c] + b[c];
        if (out)  out[(size_t)row * DMODEL + c] = o;
        if (outb) outb[(size_t)row * DMODEL + c] = f2b(o);
    }
}

// ---------------------------------------------------------------- de-norm + transpose
__global__ void final_k(const float* __restrict__ dec, const float* __restrict__ meanb,
                        const float* __restrict__ stdb, float* __restrict__ out,
                        int b0, int CB) {
    int idx = blockIdx.x * blockDim.x + threadIdx.x;
    if (idx >= CB * LFUT * NVARS) return;
    int n = idx % NVARS;
    int r = idx / NVARS;
    int l = r % LFUT;
    int bl = r / LFUT;
    int tok = bl * NVARS + n;
    out[(size_t)((b0 + bl) * LFUT + l) * NVARS + n] =
        dec[(size_t)tok * LFUT + l] * stdb[tok] + meanb[tok];
}

// ---------------------------------------------------------------- launch
extern "C" void kernel_launch(void* const* d_in, const int* in_sizes, int n_in,
                              void* d_out, int out_size, void* d_ws, size_t ws_size,
                              hipStream_t stream) {
    const float* hist    = (const float*)d_in[0];
    const float* emb_w   = (const float*)d_in[1];
    const float* emb_b   = (const float*)d_in[2];
    const float* m_in_w  = (const float*)d_in[3];
    const float* m_conv_w= (const float*)d_in[4];
    const float* m_conv_b= (const float*)d_in[5];
    const float* m_x_w   = (const float*)d_in[6];
    const float* m_dt_w  = (const float*)d_in[7];
    const float* m_dt_b  = (const float*)d_in[8];
    const float* m_A_log = (const float*)d_in[9];
    const float* m_D     = (const float*)d_in[10];
    const float* m_out_w = (const float*)d_in[11];
    const float* ffn_w1  = (const float*)d_in[12];
    const float* ffn_b1  = (const float*)d_in[13];
    const float* ffn_w2  = (const float*)d_in[14];
    const float* ffn_b2  = (const float*)d_in[15];
    const float* norm1_w = (const float*)d_in[16];
    const float* norm1_b = (const float*)d_in[17];
    const float* norm2_w = (const float*)d_in[18];
    const float* norm2_b = (const float*)d_in[19];
    const float* normf_w = (const float*)d_in[20];
    const float* normf_b = (const float*)d_in[21];
    const float* proj_w  = (const float*)d_in[22];
    const float* proj_b  = (const float*)d_in[23];

    float* out = (float*)d_out;
    float* ws  = (float*)d_ws;

    // bf16 weight pool element count
    const size_t WTSE = 4u*1024*512 + 4u*512*512 + 2u*512*512 + 2u*512*512
                      + 96u*512 + 4u*96*512 + 4u*512*32 + 96u*512;

    // adaptive CB so footprint fits ws_size
    int CB = BATCH;
    for (;;) {
        size_t R = (size_t)CB * NVARS, NP = (size_t)CB * DINNER;
        size_t Rp = (R + 3) & ~3ull;
        size_t fl = R * 2144 + 2 * Rp + (size_t)SCAN_C * 33 * NP;
        size_t us = R * 1728 + WTSE;
        if (fl * 4 + us * 2 + 1024 <= ws_size || CB == 1) break;
        CB >>= 1;
    }
    const int R  = CB * NVARS;
    const int NP = CB * DINNER;
    const size_t Rp = ((size_t)R + 3) & ~3ull;

    float* uz    = ws;                                    // [R][1024]
    float* x     = uz + (size_t)R * 1024;                 // [R][512]
    float* accb  = x + (size_t)R * 512;                   // [R][512]
    float* xdbc  = accb + (size_t)R * 512;                // [R][96]
    float* meanb = xdbc + (size_t)R * 96;                 // [Rp]
    float* stdb  = meanb + Rp;                            // [Rp]
    float* Hpart = stdb + Rp;                             // [C][32][NP]
    float* Sd    = Hpart + (size_t)SCAN_C * DSTATE * NP;  // [C][NP]
    ushort* xb    = (ushort*)(Sd + (size_t)SCAN_C * NP);  // [R][512]
    ushort* ybmid = xb + (size_t)R * 512;                 // [R][512]
    ushort* ucb   = ybmid + (size_t)R * 512;              // [R][512]
    ushort* xinb  = ucb + (size_t)R * 512;                // [R][96]
    ushort* xdbcb = xinb + (size_t)R * 96;                // [R][96]
    ushort* wts   = xdbcb + (size_t)R * 96;

    ushort *inw_t[4], *outw_t[4], *f1_t[2], *f2_t[2], *emb_t, *xw_t[4], *dtw_t[4], *proj_t;
    {
        ushort* p = wts;
        for (int i = 0; i < 4; i++) { inw_t[i]  = p; p += (size_t)1024 * 512; }
        for (int i = 0; i < 4; i++) { outw_t[i] = p; p += (size_t)512 * 512; }
        for (int i = 0; i < 2; i++) { f1_t[i]   = p; p += (size_t)512 * 512; }
        for (int i = 0; i < 2; i++) { f2_t[i]   = p; p += (size_t)512 * 512; }
        emb_t = p; p += (size_t)512 * 96;
        for (int i = 0; i < 4; i++) { xw_t[i]   = p; p += (size_t)96 * 512; }
        for (int i = 0; i < 4; i++) { dtw_t[i]  = p; p += (size_t)512 * 32; }
        proj_t = p;
    }

    for (int i = 0; i < 4; i++)
        castT_k<<<(512 * 1024 + 255) / 256, 256, 0, stream>>>(
            m_in_w + (size_t)i * 512 * 1024, inw_t[i], 512, 1024);
    for (int i = 0; i < 4; i++)
        castT_k<<<(512 * 512 + 255) / 256, 256, 0, stream>>>(
            m_out_w + (size_t)i * 512 * 512, outw_t[i], 512, 512);
    for (int i = 0; i < 2; i++)
        castT_k<<<(512 * 512 + 255) / 256, 256, 0, stream>>>(
            ffn_w1 + (size_t)i * 512 * 512, f1_t[i], 512, 512);
    for (int i = 0; i < 2; i++)
        castT_k<<<(512 * 512 + 255) / 256, 256, 0, stream>>>(
            ffn_w2 + (size_t)i * 512 * 512, f2_t[i], 512, 512);
    castT_k<<<(96 * 512 + 255) / 256, 256, 0, stream>>>(emb_w, emb_t, 96, 512);
    for (int i = 0; i < 4; i++)
        castT_k<<<(512 * 96 + 255) / 256, 256, 0, stream>>>(
            m_x_w + (size_t)i * 512 * 96, xw_t[i], 512, 96);
    for (int i = 0; i < 4; i++)
        castT_k<<<(32 * 512 + 255) / 256, 256, 0, stream>>>(
            m_dt_w + (size_t)i * 32 * 512, dtw_t[i], 32, 512);
    castT_k<<<(512 * 96 + 255) / 256, 256, 0, stream>>>(proj_w, proj_t, 512, 96);

    auto bgemm = [&](const ushort* A, int lda, const ushort* Bt, int ldb,
                     const float* bias, float* C, int ldc, ushort* C2, int ldc2,
                     int M, int N, int K, int act, int accum) {
        dim3 grid((N + TBN - 1) / TBN, (M + TBM - 1) / TBM);
        bgemm_k<<<grid, 256, 0, stream>>>(A, lda, Bt, ldb, bias, C, ldc, C2, ldc2,
                                          M, N, K, act, accum);
    };

    for (int b0 = 0; b0 < BATCH; b0 += CB) {
        meanstd_k<<<(R + 255) / 256, 256, 0, stream>>>(hist, xinb, meanb, stdb, b0, CB);
        bgemm(xinb, 96, emb_t, 96, emb_b, x, 512, xb, 512, R, 512, 96, 0, 0);

        for (int l = 0; l < 2; l++) {
            for (int dir = 0; dir < 2; dir++) {
                int p = l * 2 + dir;
                const float* cw   = m_conv_w + (size_t)p * DINNER * 2;
                const float* cb   = m_conv_b + (size_t)p * DINNER;
                const float* dtb  = m_dt_b  + (size_t)p * DINNER;
                const float* alog = m_A_log + (size_t)p * DINNER * DSTATE;
                const float* Dp   = m_D     + (size_t)p * DINNER;

                // uz = x @ in_w   [R][1024]
                bgemm(xb, 512, inw_t[p], 512, nullptr, uz, 1024, nullptr, 0,
                      R, 1024, 512, 0, 0);
                // ucb = bf16(silu(conv(u)))
                convsilu_k<<<(unsigned)(((size_t)R * DINNER + 255) / 256), 256, 0, stream>>>(
                    uz, cw, cb, ucb, dir, R);
                // xdbc = uc @ x_w  (fp32 for scan B/C + bf16 for dt-proj)
                bgemm(ucb, 512, xw_t[p], 512, nullptr, xdbc, 96, xdbcb, 96,
                      R, 96, 512, 0, 0);
                // delta = softplus(dt @ dt_w + dt_b) -> uz[:,0:512]
                bgemm(xdbcb, 96, dtw_t[p], 32, dtb, uz, 1024, nullptr, 0,
                      R, 512, 32, 2, 0);
                // chunked scan
                scan_part_k<<<(NP * SCAN_C + 255) / 256, 256, 0, stream>>>(
                    uz, ucb, xdbc, alog, Hpart, Sd, dir, CB);
                scan_carry_k<<<(NP * DSTATE + 255) / 256, 256, 0, stream>>>(
                    Hpart, Sd, alog, CB);
                scan_final_k<<<(NP * SCAN_C + 255) / 256, 256, 0, stream>>>(
                    uz, ucb, xdbc, alog, Dp, Hpart, ybmid, dir, CB);
                // acc (=)+= y @ out_w
                bgemm(ybmid, 512, outw_t[p], 512, nullptr, accb, 512, nullptr, 0,
                      R, 512, 512, 0, dir);
            }
            ln_k<<<R, 64, 0, stream>>>(accb, x, norm1_w + l * DMODEL, norm1_b + l * DMODEL,
                                       x, xb);
            bgemm(xb, 512, f1_t[l], 512, ffn_b1 + l * DMODEL, nullptr, 0, ybmid, 512,
                  R, 512, 512, 1, 0);
            bgemm(ybmid, 512, f2_t[l], 512, ffn_b2 + l * DMODEL, accb, 512, nullptr, 0,
                  R, 512, 512, 0, 0);
            ln_k<<<R, 64, 0, stream>>>(x, accb, norm2_w + l * DMODEL, norm2_b + l * DMODEL,
                                       x, xb);
        }

        ln_k<<<R, 64, 0, stream>>>(x, nullptr, normf_w, normf_b, nullptr, xb);
        bgemm(xb, 512, proj_t, 512, proj_b, xdbc, 96, nullptr, 0, R, 96, 512, 0, 0);
        final_k<<<(CB * LFUT * NVARS + 255) / 256, 256, 0, stream>>>(
            xdbc, meanb, stdb, out, b0, CB);
    }
}

// Round 7
// 3069.217 us; speedup vs baseline: 4.5605x; 1.0170x over previous
//
#include <hip/hip_runtime.h>
#include <math.h>

#define BATCH 32
#define LHIST 96
#define NVARS 862
#define LFUT  96
#define DMODEL 512
#define DINNER 512
#define DSTATE 32
#define DTRANK 32
#define SCAN_C 32
#define SCAN_TC ((NVARS + SCAN_C - 1) / SCAN_C)   // 27

typedef short short8 __attribute__((ext_vector_type(8)));
typedef float floatx4 __attribute__((ext_vector_type(4)));
typedef unsigned short ushort;

#define LOG2E 1.44269504088896f

static __device__ __forceinline__ ushort f2b(float f) {
    unsigned u = __builtin_bit_cast(unsigned, f);
    unsigned r = (u + 0x7FFFu + ((u >> 16) & 1u)) >> 16;
    return (ushort)r;
}
static __device__ __forceinline__ float b2f(ushort h) {
    unsigned u = ((unsigned)h) << 16;
    return __builtin_bit_cast(float, u);
}

// ---------------------------------------------------------------- mean/std
__global__ void meanstd_k(const float* __restrict__ hist, ushort* __restrict__ xinb,
                          float* __restrict__ meanb, float* __restrict__ stdb,
                          int b0, int CB) {
    int idx = blockIdx.x * blockDim.x + threadIdx.x;
    if (idx >= CB * NVARS) return;
    int b = b0 + idx / NVARS, n = idx % NVARS;
    const float* p = hist + (size_t)b * LHIST * NVARS + n;
    float s = 0.f;
    for (int l = 0; l < LHIST; l++) s += p[(size_t)l * NVARS];
    float mean = s * (1.f / LHIST);
    float v = 0.f;
    for (int l = 0; l < LHIST; l++) { float d = p[(size_t)l * NVARS] - mean; v += d * d; }
    v *= (1.f / LHIST);
    float sd = sqrtf(v + 1e-5f);
    float inv = 1.f / sd;
    meanb[idx] = mean;
    stdb[idx]  = sd;
    ushort* o = xinb + (size_t)idx * LHIST;
    for (int l = 0; l < LHIST; l++) o[l] = f2b((p[(size_t)l * NVARS] - mean) * inv);
}

// ---------------------------------------------------------------- weight cast+transpose
__global__ void castT_k(const float* __restrict__ W, ushort* __restrict__ Wt,
                        int K, int N) {
    int idx = blockIdx.x * blockDim.x + threadIdx.x;
    if (idx >= K * N) return;
    int k = idx / N, n = idx % N;
    Wt[(size_t)n * K + k] = f2b(W[idx]);
}

// ---------------------------------------------------------------- bf16 MFMA GEMM
// C[M,N] = act(A[M,K]bf16 @ Bt[N,K]^T + bias) (+C). act: 0 none, 1 relu, 2 softplus.
#define TBM 128
#define TBN 128
#define TBK 32

__global__ __launch_bounds__(256)
void bgemm_k(const ushort* __restrict__ A, int lda,
             const ushort* __restrict__ Bt, int ldb,
             const float* __restrict__ bias,
             float* __restrict__ C, int ldc,
             ushort* __restrict__ C2, int ldc2,
             int M, int N, int K, int act, int accum) {
    __shared__ ushort As[TBM][TBK];
    __shared__ ushort Bs[TBN][TBK];
    int tid = threadIdx.x;
    int gm0 = blockIdx.y * TBM, gn0 = blockIdx.x * TBN;
    int lane = tid & 63, w = tid >> 6;
    int wm = (w >> 1) * 64, wn = (w & 1) * 64;
    int col16 = lane & 15, quad = lane >> 4;

    floatx4 acc[4][4];
#pragma unroll
    for (int i = 0; i < 4; i++)
#pragma unroll
        for (int j = 0; j < 4; j++) acc[i][j] = (floatx4){0.f, 0.f, 0.f, 0.f};

    int srow = tid >> 2;
    int schunk = (tid & 3) * 8;

    for (int k0 = 0; k0 < K; k0 += TBK) {
        int ra0 = min(gm0 + srow, M - 1);
        int ra1 = min(gm0 + srow + 64, M - 1);
        short8 a0 = *(const short8*)(A + (size_t)ra0 * lda + k0 + schunk);
        short8 a1 = *(const short8*)(A + (size_t)ra1 * lda + k0 + schunk);
        int rb0 = min(gn0 + srow, N - 1);
        int rb1 = min(gn0 + srow + 64, N - 1);
        short8 b0 = *(const short8*)(Bt + (size_t)rb0 * ldb + k0 + schunk);
        short8 b1 = *(const short8*)(Bt + (size_t)rb1 * ldb + k0 + schunk);
        __syncthreads();
        *(short8*)&As[srow][schunk]      = a0;
        *(short8*)&As[srow + 64][schunk] = a1;
        *(short8*)&Bs[srow][schunk]      = b0;
        *(short8*)&Bs[srow + 64][schunk] = b1;
        __syncthreads();

        short8 af[4], bf[4];
#pragma unroll
        for (int mt = 0; mt < 4; mt++)
            af[mt] = *(const short8*)&As[wm + mt * 16 + col16][quad * 8];
#pragma unroll
        for (int nt = 0; nt < 4; nt++)
            bf[nt] = *(const short8*)&Bs[wn + nt * 16 + col16][quad * 8];
#pragma unroll
        for (int mt = 0; mt < 4; mt++)
#pragma unroll
            for (int nt = 0; nt < 4; nt++)
                acc[mt][nt] = __builtin_amdgcn_mfma_f32_16x16x32_bf16(
                    af[mt], bf[nt], acc[mt][nt], 0, 0, 0);
    }

    int rbase = gm0 + wm + quad * 4;
    int cbase = gn0 + wn + col16;
#pragma unroll
    for (int mt = 0; mt < 4; mt++) {
#pragma unroll
        for (int reg = 0; reg < 4; reg++) {
            int r = rbase + mt * 16 + reg;
            if (r >= M) continue;
#pragma unroll
            for (int nt = 0; nt < 4; nt++) {
                int c = cbase + nt * 16;
                if (c >= N) continue;
                float v = acc[mt][nt][reg];
                if (bias) v += bias[c];
                if (act == 1) v = fmaxf(v, 0.f);
                else if (act == 2) v = (v > 20.f) ? v : log1pf(expf(v));
                if (accum) v += C[(size_t)r * ldc + c];
                if (C)  C[(size_t)r * ldc + c] = v;
                if (C2) C2[(size_t)r * ldc2 + c] = f2b(v);
            }
        }
    }
}

// ---------------------------------------------------------------- conv+silu (bf16 in/out, x8)
// u = uzb[:, 0:512] (stride 1024, bf16). Writes bf16 ucb [R][512].
__global__ void conv8_k(const ushort* __restrict__ uzb, const float* __restrict__ cw,
                        const float* __restrict__ cb, ushort* __restrict__ ucb,
                        int rev, int R) {
    int idx = blockIdx.x * blockDim.x + threadIdx.x;
    if (idx >= R * 64) return;
    int m = idx >> 6;
    int e0 = (idx & 63) * 8;
    int t = m % NVARS;
    const ushort* up = uzb + (size_t)m * 1024 + e0;
    short8 cur = *(const short8*)up;
    short8 oth = (short8){0,0,0,0,0,0,0,0};
    if (!rev) { if (t > 0)          oth = *(const short8*)(up - 1024); }
    else      { if (t < NVARS - 1)  oth = *(const short8*)(up + 1024); }
    short8 res;
#pragma unroll
    for (int i = 0; i < 8; i++) {
        int e = e0 + i;
        float v = cw[e * 2] * b2f((ushort)oth[i]) + cw[e * 2 + 1] * b2f((ushort)cur[i]) + cb[e];
        float sig = 1.f / (1.f + __expf(-v));
        res[i] = (short)f2b(v * sig);
    }
    *(short8*)(ucb + (size_t)m * 512 + e0) = res;
}

// ---------------------------------------------------------------- chunked scan
// delta bf16 in deltab, z bf16 in uzb[:,512:], u bf16 in ucb, B/C fp32 in xdbc.
// A_log = log(1..32) -> A[s] = -(s+1): exp(d*A[s]) = q^(s+1), q = exp(-d).
// Powers via 4 independent chains (q,q2,q3,q4 stepped by q4) -> dep depth 8 not 31.

// Pass A: local scan from h=0 -> Hpart[c][s][be], Sd[c][be]
__global__ __launch_bounds__(256)
void scan_part_k(const ushort* __restrict__ deltab, const ushort* __restrict__ ucb,
                 const float* __restrict__ xdbc, const float* __restrict__ A_log,
                 float* __restrict__ Hpart, float* __restrict__ Sd,
                 int rev, int CB) {
    int NP = CB * DINNER;
    int idx = blockIdx.x * blockDim.x + threadIdx.x;
    if (idx >= NP * SCAN_C) return;
    int c = idx / NP, be = idx % NP;
    int b = be >> 9, e = be & (DINNER - 1);

    float A[DSTATE], h[DSTATE];
    bool fastA = true;
#pragma unroll
    for (int s = 0; s < DSTATE; s++) {
        float a = -__expf(A_log[e * DSTATE + s]);
        fastA = fastA && (fabsf(a + (float)(s + 1)) < 1e-3f * (s + 1));
        A[s] = a * LOG2E;
        h[s] = 0.f;
    }
    float sd = 0.f;
    int tau1 = min((c + 1) * SCAN_TC, NVARS);
    if (fastA) {
        for (int tau = c * SCAN_TC; tau < tau1; tau++) {
            int t = rev ? (NVARS - 1 - tau) : tau;
            size_t m = (size_t)b * NVARS + t;
            float d  = b2f(deltab[m * 512 + e]);
            float uv = b2f(ucb[m * 512 + e]);
            float du = d * uv;
            sd += d;
            const float* Bp = xdbc + m * 96 + DTRANK;
            float q = __expf(-d);
            float q2 = q * q;
            float q4 = q2 * q2;
            float p0 = q, p1 = q2, p2 = q2 * q, p3 = q4;
#pragma unroll
            for (int g = 0; g < 8; g++) {
                h[4*g+0] = p0 * h[4*g+0] + du * Bp[4*g+0];
                h[4*g+1] = p1 * h[4*g+1] + du * Bp[4*g+1];
                h[4*g+2] = p2 * h[4*g+2] + du * Bp[4*g+2];
                h[4*g+3] = p3 * h[4*g+3] + du * Bp[4*g+3];
                if (g < 7) { p0 *= q4; p1 *= q4; p2 *= q4; p3 *= q4; }
            }
        }
    } else {
        for (int tau = c * SCAN_TC; tau < tau1; tau++) {
            int t = rev ? (NVARS - 1 - tau) : tau;
            size_t m = (size_t)b * NVARS + t;
            float d  = b2f(deltab[m * 512 + e]);
            float uv = b2f(ucb[m * 512 + e]);
            float du = d * uv;
            sd += d;
            const float* Bp = xdbc + m * 96 + DTRANK;
#pragma unroll
            for (int s = 0; s < DSTATE; s++)
                h[s] = exp2f(d * A[s]) * h[s] + du * Bp[s];
        }
    }
    Sd[(size_t)c * NP + be] = sd;
#pragma unroll
    for (int s = 0; s < DSTATE; s++)
        Hpart[((size_t)c * DSTATE + s) * NP + be] = h[s];
}

// Pass B: thread per (s, be); carry across chunks; Hpart -> carry-in (in place).
__global__ __launch_bounds__(256)
void scan_carry_k(float* __restrict__ Hpart, const float* __restrict__ Sd,
                  const float* __restrict__ A_log, int CB) {
    int NP = CB * DINNER;
    int idx = blockIdx.x * blockDim.x + threadIdx.x;
    if (idx >= NP * DSTATE) return;
    int s = idx / NP, be = idx % NP;
    int e = be & (DINNER - 1);
    float a2 = -__expf(A_log[e * DSTATE + s]) * LOG2E;
    float carry = 0.f;
    for (int c = 0; c < SCAN_C; c++) {
        float sd = Sd[(size_t)c * NP + be];
        size_t off = ((size_t)c * DSTATE + s) * NP + be;
        float hp = Hpart[off];
        Hpart[off] = carry;
        carry = hp + exp2f(a2 * sd) * carry;
    }
}

// Pass C: rerun local scan seeded with carry-in; emit gated y as bf16.
__global__ __launch_bounds__(256)
void scan_final_k(const ushort* __restrict__ deltab, const ushort* __restrict__ uzb,
                  const ushort* __restrict__ ucb, const float* __restrict__ xdbc,
                  const float* __restrict__ A_log, const float* __restrict__ Dp,
                  const float* __restrict__ CarryIn, ushort* __restrict__ yb,
                  int rev, int CB) {
    int NP = CB * DINNER;
    int idx = blockIdx.x * blockDim.x + threadIdx.x;
    if (idx >= NP * SCAN_C) return;
    int c = idx / NP, be = idx % NP;
    int b = be >> 9, e = be & (DINNER - 1);

    float A[DSTATE], h[DSTATE];
    bool fastA = true;
#pragma unroll
    for (int s = 0; s < DSTATE; s++) {
        float a = -__expf(A_log[e * DSTATE + s]);
        fastA = fastA && (fabsf(a + (float)(s + 1)) < 1e-3f * (s + 1));
        A[s] = a * LOG2E;
        h[s] = CarryIn[((size_t)c * DSTATE + s) * NP + be];
    }
    float Dv = Dp[e];
    int tau1 = min((c + 1) * SCAN_TC, NVARS);
    if (fastA) {
        for (int tau = c * SCAN_TC; tau < tau1; tau++) {
            int t = rev ? (NVARS - 1 - tau) : tau;
            size_t m = (size_t)b * NVARS + t;
            float d  = b2f(deltab[m * 512 + e]);
            float zz = b2f(uzb[m * 1024 + 512 + e]);
            float uv = b2f(ucb[m * 512 + e]);
            float du = d * uv;
            const float* Bp = xdbc + m * 96 + DTRANK;
            const float* Cp = Bp + DSTATE;
            float q = __expf(-d);
            float q2 = q * q;
            float q4 = q2 * q2;
            float p0 = q, p1 = q2, p2 = q2 * q, p3 = q4;
            float a0 = 0.f, a1 = 0.f, a2 = 0.f, a3 = 0.f;
#pragma unroll
            for (int g = 0; g < 8; g++) {
                h[4*g+0] = p0 * h[4*g+0] + du * Bp[4*g+0];
                h[4*g+1] = p1 * h[4*g+1] + du * Bp[4*g+1];
                h[4*g+2] = p2 * h[4*g+2] + du * Bp[4*g+2];
                h[4*g+3] = p3 * h[4*g+3] + du * Bp[4*g+3];
                a0 += h[4*g+0] * Cp[4*g+0];
                a1 += h[4*g+1] * Cp[4*g+1];
                a2 += h[4*g+2] * Cp[4*g+2];
                a3 += h[4*g+3] * Cp[4*g+3];
                if (g < 7) { p0 *= q4; p1 *= q4; p2 *= q4; p3 *= q4; }
            }
            float accv = (a0 + a1) + (a2 + a3);
            float sig = 1.f / (1.f + __expf(-zz));
            yb[m * 512 + e] = f2b((accv + uv * Dv) * (zz * sig));
        }
    } else {
        for (int tau = c * SCAN_TC; tau < tau1; tau++) {
            int t = rev ? (NVARS - 1 - tau) : tau;
            size_t m = (size_t)b * NVARS + t;
            float d  = b2f(deltab[m * 512 + e]);
            float zz = b2f(uzb[m * 1024 + 512 + e]);
            float uv = b2f(ucb[m * 512 + e]);
            float du = d * uv;
            const float* Bp = xdbc + m * 96 + DTRANK;
            const float* Cp = Bp + DSTATE;
            float accv = 0.f;
#pragma unroll
            for (int s = 0; s < DSTATE; s++) {
                h[s] = exp2f(d * A[s]) * h[s] + du * Bp[s];
                accv += h[s] * Cp[s];
            }
            float sig = 1.f / (1.f + __expf(-zz));
            yb[m * 512 + e] = f2b((accv + uv * Dv) * (zz * sig));
        }
    }
}

// ---------------------------------------------------------------- layernorm
__global__ __launch_bounds__(64)
void ln_k(const float* __restrict__ in1, const float* __restrict__ in2,
          const float* __restrict__ w, const float* __restrict__ b,
          float* __restrict__ out, ushort* __restrict__ outb) {
    int row = blockIdx.x;
    int lane = threadIdx.x;
    const float* p1 = in1 + (size_t)row * DMODEL;
    const float* p2 = in2 ? in2 + (size_t)row * DMODEL : nullptr;
    float v[8];
#pragma unroll
    for (int i = 0; i < 8; i++) {
        int c = lane + i * 64;
        v[i] = p1[c];
        if (p2) v[i] += p2[c];
    }
    float s = 0.f;
#pragma unroll
    for (int i = 0; i < 8; i++) s += v[i];
#pragma unroll
    for (int off = 32; off >= 1; off >>= 1) s += __shfl_xor(s, off);
    float mean = s * (1.f / DMODEL);
    float q = 0.f;
#pragma unroll
    for (int i = 0; i < 8; i++) { float d = v[i] - mean; q += d * d; }
#pragma unroll
    for (int off = 32; off >= 1; off >>= 1) q += __shfl_xor(q, off);
    float rs = rsqrtf(q * (1.f / DMODEL) + 1e-5f);
#pragma unroll
    for (int i = 0; i < 8; i++) {
        int c = lane + i * 64;
        float o = (v[i] - mean) * rs * w[c] + b[c];
        if (out)  out[(size_t)row * DMODEL + c] = o;
        if (outb) outb[(size_t)row * DMODEL + c] = f2b(o);
    }
}

// ---------------------------------------------------------------- de-norm + transpose
__global__ void final_k(const float* __restrict__ dec, const float* __restrict__ meanb,
                        const float* __restrict__ stdb, float* __restrict__ out,
                        int b0, int CB) {
    int idx = blockIdx.x * blockDim.x + threadIdx.x;
    if (idx >= CB * LFUT * NVARS) return;
    int n = idx % NVARS;
    int r = idx / NVARS;
    int l = r % LFUT;
    int bl = r / LFUT;
    int tok = bl * NVARS + n;
    out[(size_t)((b0 + bl) * LFUT + l) * NVARS + n] =
        dec[(size_t)tok * LFUT + l] * stdb[tok] + meanb[tok];
}

// ---------------------------------------------------------------- launch
extern "C" void kernel_launch(void* const* d_in, const int* in_sizes, int n_in,
                              void* d_out, int out_size, void* d_ws, size_t ws_size,
                              hipStream_t stream) {
    const float* hist    = (const float*)d_in[0];
    const float* emb_w   = (const float*)d_in[1];
    const float* emb_b   = (const float*)d_in[2];
    const float* m_in_w  = (const float*)d_in[3];
    const float* m_conv_w= (const float*)d_in[4];
    const float* m_conv_b= (const float*)d_in[5];
    const float* m_x_w   = (const float*)d_in[6];
    const float* m_dt_w  = (const float*)d_in[7];
    const float* m_dt_b  = (const float*)d_in[8];
    const float* m_A_log = (const float*)d_in[9];
    const float* m_D     = (const float*)d_in[10];
    const float* m_out_w = (const float*)d_in[11];
    const float* ffn_w1  = (const float*)d_in[12];
    const float* ffn_b1  = (const float*)d_in[13];
    const float* ffn_w2  = (const float*)d_in[14];
    const float* ffn_b2  = (const float*)d_in[15];
    const float* norm1_w = (const float*)d_in[16];
    const float* norm1_b = (const float*)d_in[17];
    const float* norm2_w = (const float*)d_in[18];
    const float* norm2_b = (const float*)d_in[19];
    const float* normf_w = (const float*)d_in[20];
    const float* normf_b = (const float*)d_in[21];
    const float* proj_w  = (const float*)d_in[22];
    const float* proj_b  = (const float*)d_in[23];

    float* out = (float*)d_out;
    float* ws  = (float*)d_ws;

    const size_t WTSE = 4u*1024*512 + 4u*512*512 + 2u*512*512 + 2u*512*512
                      + 96u*512 + 4u*96*512 + 4u*512*32 + 96u*512;

    // adaptive CB so footprint fits ws_size
    int CB = BATCH;
    for (;;) {
        size_t R = (size_t)CB * NVARS, NP = (size_t)CB * DINNER;
        size_t Rp = (R + 3) & ~3ull;
        size_t fl = R * 1120 + 2 * Rp + (size_t)SCAN_C * 33 * NP;   // fp32 elems
        size_t us = R * 3264 + WTSE;                                 // bf16 elems
        if (fl * 4 + us * 2 + 1024 <= ws_size || CB == 1) break;
        CB >>= 1;
    }
    const int R  = CB * NVARS;
    const int NP = CB * DINNER;
    const size_t Rp = ((size_t)R + 3) & ~3ull;

    float* x     = ws;                                    // [R][512]
    float* accb  = x + (size_t)R * 512;                   // [R][512]
    float* xdbc  = accb + (size_t)R * 512;                // [R][96]
    float* meanb = xdbc + (size_t)R * 96;                 // [Rp]
    float* stdb  = meanb + Rp;                            // [Rp]
    float* Hpart = stdb + Rp;                             // [C][32][NP]
    float* Sd    = Hpart + (size_t)SCAN_C * DSTATE * NP;  // [C][NP]
    ushort* xb     = (ushort*)(Sd + (size_t)SCAN_C * NP); // [R][512]
    ushort* ybmid  = xb + (size_t)R * 512;                // [R][512]
    ushort* ucb    = ybmid + (size_t)R * 512;             // [R][512]
    ushort* uzb    = ucb + (size_t)R * 512;               // [R][1024]
    ushort* deltab = uzb + (size_t)R * 1024;              // [R][512]
    ushort* xinb   = deltab + (size_t)R * 512;            // [R][96]
    ushort* xdbcb  = xinb + (size_t)R * 96;               // [R][96]
    ushort* wts    = xdbcb + (size_t)R * 96;

    ushort *inw_t[4], *outw_t[4], *f1_t[2], *f2_t[2], *emb_t, *xw_t[4], *dtw_t[4], *proj_t;
    {
        ushort* p = wts;
        for (int i = 0; i < 4; i++) { inw_t[i]  = p; p += (size_t)1024 * 512; }
        for (int i = 0; i < 4; i++) { outw_t[i] = p; p += (size_t)512 * 512; }
        for (int i = 0; i < 2; i++) { f1_t[i]   = p; p += (size_t)512 * 512; }
        for (int i = 0; i < 2; i++) { f2_t[i]   = p; p += (size_t)512 * 512; }
        emb_t = p; p += (size_t)512 * 96;
        for (int i = 0; i < 4; i++) { xw_t[i]   = p; p += (size_t)96 * 512; }
        for (int i = 0; i < 4; i++) { dtw_t[i]  = p; p += (size_t)512 * 32; }
        proj_t = p;
    }

    for (int i = 0; i < 4; i++)
        castT_k<<<(512 * 1024 + 255) / 256, 256, 0, stream>>>(
            m_in_w + (size_t)i * 512 * 1024, inw_t[i], 512, 1024);
    for (int i = 0; i < 4; i++)
        castT_k<<<(512 * 512 + 255) / 256, 256, 0, stream>>>(
            m_out_w + (size_t)i * 512 * 512, outw_t[i], 512, 512);
    for (int i = 0; i < 2; i++)
        castT_k<<<(512 * 512 + 255) / 256, 256, 0, stream>>>(
            ffn_w1 + (size_t)i * 512 * 512, f1_t[i], 512, 512);
    for (int i = 0; i < 2; i++)
        castT_k<<<(512 * 512 + 255) / 256, 256, 0, stream>>>(
            ffn_w2 + (size_t)i * 512 * 512, f2_t[i], 512, 512);
    castT_k<<<(96 * 512 + 255) / 256, 256, 0, stream>>>(emb_w, emb_t, 96, 512);
    for (int i = 0; i < 4; i++)
        castT_k<<<(512 * 96 + 255) / 256, 256, 0, stream>>>(
            m_x_w + (size_t)i * 512 * 96, xw_t[i], 512, 96);
    for (int i = 0; i < 4; i++)
        castT_k<<<(32 * 512 + 255) / 256, 256, 0, stream>>>(
            m_dt_w + (size_t)i * 32 * 512, dtw_t[i], 32, 512);
    castT_k<<<(512 * 96 + 255) / 256, 256, 0, stream>>>(proj_w, proj_t, 512, 96);

    auto bgemm = [&](const ushort* A, int lda, const ushort* Bt, int ldb,
                     const float* bias, float* C, int ldc, ushort* C2, int ldc2,
                     int M, int N, int K, int act, int accum) {
        dim3 grid((N + TBN - 1) / TBN, (M + TBM - 1) / TBM);
        bgemm_k<<<grid, 256, 0, stream>>>(A, lda, Bt, ldb, bias, C, ldc, C2, ldc2,
                                          M, N, K, act, accum);
    };

    for (int b0 = 0; b0 < BATCH; b0 += CB) {
        meanstd_k<<<(R + 255) / 256, 256, 0, stream>>>(hist, xinb, meanb, stdb, b0, CB);
        bgemm(xinb, 96, emb_t, 96, emb_b, x, 512, xb, 512, R, 512, 96, 0, 0);

        for (int l = 0; l < 2; l++) {
            for (int dir = 0; dir < 2; dir++) {
                int p = l * 2 + dir;
                const float* cw   = m_conv_w + (size_t)p * DINNER * 2;
                const float* cb   = m_conv_b + (size_t)p * DINNER;
                const float* dtb  = m_dt_b  + (size_t)p * DINNER;
                const float* alog = m_A_log + (size_t)p * DINNER * DSTATE;
                const float* Dp   = m_D     + (size_t)p * DINNER;

                // uzb = bf16(x @ in_w)   [R][1024] (u | z)
                bgemm(xb, 512, inw_t[p], 512, nullptr, nullptr, 0, uzb, 1024,
                      R, 1024, 512, 0, 0);
                // ucb = bf16(silu(conv(u)))
                conv8_k<<<(R * 64 + 255) / 256, 256, 0, stream>>>(uzb, cw, cb, ucb, dir, R);
                // xdbc = uc @ x_w  (fp32 B/C for scan + bf16 dt for dt-proj)
                bgemm(ucb, 512, xw_t[p], 512, nullptr, xdbc, 96, xdbcb, 96,
                      R, 96, 512, 0, 0);
                // deltab = bf16(softplus(dt @ dt_w + dt_b))
                bgemm(xdbcb, 96, dtw_t[p], 32, dtb, nullptr, 0, deltab, 512,
                      R, 512, 32, 2, 0);
                // chunked scan
                scan_part_k<<<(NP * SCAN_C + 255) / 256, 256, 0, stream>>>(
                    deltab, ucb, xdbc, alog, Hpart, Sd, dir, CB);
                scan_carry_k<<<(NP * DSTATE + 255) / 256, 256, 0, stream>>>(
                    Hpart, Sd, alog, CB);
                scan_final_k<<<(NP * SCAN_C + 255) / 256, 256, 0, stream>>>(
                    deltab, uzb, ucb, xdbc, alog, Dp, Hpart, ybmid, dir, CB);
                // acc (=)+= y @ out_w
                bgemm(ybmid, 512, outw_t[p], 512, nullptr, accb, 512, nullptr, 0,
                      R, 512, 512, 0, dir);
            }
            ln_k<<<R, 64, 0, stream>>>(accb, x, norm1_w + l * DMODEL, norm1_b + l * DMODEL,
                                       x, xb);
            bgemm(xb, 512, f1_t[l], 512, ffn_b1 + l * DMODEL, nullptr, 0, ybmid, 512,
                  R, 512, 512, 1, 0);
            bgemm(ybmid, 512, f2_t[l], 512, ffn_b2 + l * DMODEL, accb, 512, nullptr, 0,
                  R, 512, 512, 0, 0);
            ln_k<<<R, 64, 0, stream>>>(x, accb, norm2_w + l * DMODEL, norm2_b + l * DMODEL,
                                       x, xb);
        }

        ln_k<<<R, 64, 0, stream>>>(x, nullptr, normf_w, normf_b, nullptr, xb);
        bgemm(xb, 512, proj_t, 512, proj_b, xdbc, 96, nullptr, 0, R, 96, 512, 0, 0);
        final_k<<<(CB * LFUT * NVARS + 255) / 256, 256, 0, stream>>>(
            xdbc, meanb, stdb, out, b0, CB);
    }
}